// Round 11
// baseline (261.033 us; speedup 1.0000x reference)
//
#include <hip/hip_runtime.h>
#include <hip/hip_bf16.h>
#include <stdint.h>

typedef unsigned short u16;
typedef __attribute__((ext_vector_type(8))) short bf16x8;
typedef __attribute__((ext_vector_type(4))) short bf16x4;
typedef __attribute__((ext_vector_type(4))) float f32x4;
typedef __attribute__((ext_vector_type(16))) float f32x16;
typedef __attribute__((ext_vector_type(4))) unsigned short u16x4;

#define DEVI static __device__ __forceinline__

DEVI u16 f2bf(float f) {
    unsigned int u = __builtin_bit_cast(unsigned int, f);
    return (u16)((u + 0x7fffu + ((u >> 16) & 1u)) >> 16);
}

DEVI float gelu_f(float v) {
    // tanh-form GELU: x * sigmoid(1.5957691(x + 0.044715 x^3)); |err vs exact| <= ~3e-4
    const float z = 1.5957691216f * (v + 0.044715f * v * v * v);
    return v / (1.0f + __expf(-z));
}

DEVI void async_copy16(const void* g, void* l) {
    __builtin_amdgcn_global_load_lds((const __attribute__((address_space(1))) void*)g,
                                     (__attribute__((address_space(3))) void*)l,
                                     16, 0, 0);
}

// ---------------- weight transpose + f32->bf16 convert: src[K][N] -> dst[N][K] ----------------
__global__ __launch_bounds__(256) void tcvt_kernel(const float* __restrict__ src,
                                                   u16* __restrict__ dst,
                                                   int K, int N) {
    __shared__ float tile[32][33];
    const int k0 = blockIdx.x * 32, n0 = blockIdx.y * 32;
    const int t = threadIdx.x;
    const int c = t & 31, r0 = t >> 5;
#pragma unroll
    for (int p = 0; p < 4; ++p) {
        const int r = r0 + p * 8;
        tile[r][c] = src[(size_t)(k0 + r) * N + n0 + c];
    }
    __syncthreads();
#pragma unroll
    for (int p = 0; p < 4; ++p) {
        const int r = r0 + p * 8;
        dst[(size_t)(n0 + r) * K + k0 + c] = f2bf(tile[c][r]);
    }
}

// ---------------- LayerNorm (f32 in) -> bf16 out ----------------
__global__ __launch_bounds__(256) void ln_kernel(const float* __restrict__ x,
                                                 const float* __restrict__ gw,
                                                 const float* __restrict__ bw,
                                                 u16* __restrict__ out) {
    const int row = blockIdx.x;
    const int t = threadIdx.x;
    const float4 v = ((const float4*)(x + (size_t)row * 1024))[t];
    float s  = v.x + v.y + v.z + v.w;
    float ss = v.x * v.x + v.y * v.y + v.z * v.z + v.w * v.w;
#pragma unroll
    for (int off = 32; off > 0; off >>= 1) {
        s  += __shfl_down(s, off);
        ss += __shfl_down(ss, off);
    }
    __shared__ float red[8];
    const int wv = t >> 6;
    if ((t & 63) == 0) { red[wv] = s; red[4 + wv] = ss; }
    __syncthreads();
    if (t == 0) {
        red[0] = red[0] + red[1] + red[2] + red[3];
        red[4] = red[4] + red[5] + red[6] + red[7];
    }
    __syncthreads();
    const float mean = red[0] * (1.0f / 1024.0f);
    const float var  = red[4] * (1.0f / 1024.0f) - mean * mean;
    const float rstd = rsqrtf(var + 1e-5f);
    const float4 gv = ((const float4*)gw)[t];
    const float4 bv = ((const float4*)bw)[t];
    u16x4 o;
    o[0] = f2bf((v.x - mean) * rstd * gv.x + bv.x);
    o[1] = f2bf((v.y - mean) * rstd * gv.y + bv.y);
    o[2] = f2bf((v.z - mean) * rstd * gv.z + bv.z);
    o[3] = f2bf((v.w - mean) * rstd * gv.w + bv.w);
    ((u16x4*)out)[(size_t)row * 256 + t] = o;
}

// ================= 128x128 GEMM, BK=64, single-buffer, m97-pure schedule =================
DEVI void stage64(const char* g, size_t ldb, char* lds0, int lane, int wv) {
    const int colsw = ((lane & 3) << 4) ^ (lane & 32);  // inverse-swizzled source col bytes
    const int rl = lane >> 2;
#pragma unroll
    for (int i = 0; i < 4; ++i) {
        const int s = wv * 4 + i;            // slot 0..15
        const int kh = s >> 3, c = s & 7;    // k-half, 16-row subtile
        async_copy16(g + (size_t)(c * 16 + rl) * ldb + kh * 64 + colsw,
                     lds0 + s * 1024);
    }
}

// EPI 0: QKV scatter. EPI 2: gelu->bf16. EPI 4: f32 partial (split-K).
template <int EPI, int SPLITK>
__global__ __launch_bounds__(256, 4) void gemmv6(const u16* __restrict__ A,
                                                 const u16* __restrict__ Bt,
                                                 const float* __restrict__ bias,
                                                 void* __restrict__ out0,
                                                 void* __restrict__ out1,
                                                 void* __restrict__ out2,
                                                 int M, int N, int K) {
    __shared__ __align__(16) char As[16384];
    __shared__ __align__(16) char Bs[16384];
    const int tid = threadIdx.x;
    const int lane = tid & 63, wv = tid >> 6;
    const int wr = wv >> 1, wc = wv & 1;        // 2M x 2N waves, 64x64 each
    const int g = lane >> 4, qq = lane & 15;
    const int rdoff = qq * 64 + ((g * 16) ^ ((qq & 8) << 2));  // swizzled read offset

    const int nwg = gridDim.x;
    int id = blockIdx.x;
    id = (id & 7) * (nwg >> 3) + (id >> 3);
    const int MT = M >> 7, NTn = N >> 7;
    const int slice = id / (MT * NTn);
    const int r2 = id % (MT * NTn);
    const int m0 = (r2 % MT) << 7;
    const int n0 = (r2 / MT) << 7;
    const int Ks = K / SPLITK;
    const int NT = Ks >> 6;
    const size_t ldb = (size_t)K * 2;

    const char* pa = (const char*)A + (size_t)m0 * ldb + (size_t)slice * Ks * 2;
    const char* pb = (const char*)Bt + (size_t)n0 * ldb + (size_t)slice * Ks * 2;

    f32x4 acc[4][4] = {};

    for (int t = 0; t < NT; ++t) {
        stage64(pa + (size_t)t * 128, ldb, As, lane, wv);
        stage64(pb + (size_t)t * 128, ldb, Bs, lane, wv);
        __syncthreads();
#pragma unroll
        for (int kh = 0; kh < 2; ++kh) {
            bf16x8 fa[4], fb[4];
#pragma unroll
            for (int fn = 0; fn < 4; ++fn)
                fb[fn] = *(const bf16x8*)(Bs + (kh * 8 + wc * 4 + fn) * 1024 + rdoff);
#pragma unroll
            for (int fm = 0; fm < 4; ++fm)
                fa[fm] = *(const bf16x8*)(As + (kh * 8 + wr * 4 + fm) * 1024 + rdoff);
#pragma unroll
            for (int fm = 0; fm < 4; ++fm)
#pragma unroll
                for (int fn = 0; fn < 4; ++fn)
                    acc[fm][fn] = __builtin_amdgcn_mfma_f32_16x16x32_bf16(fa[fm], fb[fn],
                                                                          acc[fm][fn], 0, 0, 0);
        }
        __syncthreads();
    }

#pragma unroll
    for (int fm = 0; fm < 4; ++fm) {
#pragma unroll
        for (int fn = 0; fn < 4; ++fn) {
            const int mrow = m0 + wr * 64 + fm * 16 + g * 4;
            const int ncol = n0 + wc * 64 + fn * 16 + qq;
            if constexpr (EPI == 0) {
                const float bs = bias[ncol];
                const int sec = ncol >> 10;
                const int hd_ = ncol & 1023;
                const int hh = hd_ >> 6, dd = hd_ & 63;
                if (sec == 2) {
                    const int b_ = mrow >> 11, l_ = mrow & 2047;
                    u16x4 pk;
#pragma unroll
                    for (int r = 0; r < 4; ++r) pk[r] = f2bf(acc[fm][fn][r] + bs);
                    *(u16x4*)((u16*)out2 + ((size_t)((b_ * 16 + hh) * 64 + dd)) * 2048 + l_) = pk;
                } else {
                    u16* dst = (sec == 0) ? (u16*)out0 : (u16*)out1;
                    // q-scale folds softmax 1/sqrt(hd) AND log2(e) for exp2-domain softmax
                    const float sc = (sec == 0) ? 0.1803368801f : 1.0f;
#pragma unroll
                    for (int r = 0; r < 4; ++r) {
                        const int mr = mrow + r;
                        const int b_ = mr >> 11, l_ = mr & 2047;
                        dst[((size_t)((b_ * 16 + hh) * 2048 + l_)) * 64 + dd] =
                            f2bf((acc[fm][fn][r] + bs) * sc);
                    }
                }
            } else if constexpr (EPI == 2) {
                const float bs = bias[ncol];
                u16* dst = (u16*)out0;
#pragma unroll
                for (int r = 0; r < 4; ++r)
                    dst[(size_t)(mrow + r) * N + ncol] = f2bf(gelu_f(acc[fm][fn][r] + bs));
            } else {  // EPI 4: raw f32 partial for split-K
                float* dst = (float*)out0 + (size_t)slice * M * N;
#pragma unroll
                for (int r = 0; r < 4; ++r)
                    dst[(size_t)(mrow + r) * N + ncol] = acc[fm][fn][r];
            }
        }
    }
}

// ================= 256x128 GEMM A/B test: 8 waves, BK=64, same schedule =================
// 1.33x FLOP per staged byte vs 128x128 (48KB staged per 4.2 MFLOP block-tile).
// A: 32 slots (kh*16 + c), B: 16 slots (kh*8 + c); stage 4+2 copies/lane.
template <int EPI, int SPLITK>
__global__ __launch_bounds__(512, 4) void gemm256(const u16* __restrict__ A,
                                                  const u16* __restrict__ Bt,
                                                  const float* __restrict__ bias,
                                                  void* __restrict__ out0,
                                                  int M, int N, int K) {
    __shared__ __align__(16) char As[32768];
    __shared__ __align__(16) char Bs[16384];
    const int tid = threadIdx.x;
    const int lane = tid & 63, wv = tid >> 6;
    const int wr = wv >> 1, wc = wv & 1;        // 4M x 2N waves, 64x64 each
    const int g = lane >> 4, qq = lane & 15;
    const int rdoff = qq * 64 + ((g * 16) ^ ((qq & 8) << 2));
    const int colsw = ((lane & 3) << 4) ^ (lane & 32);
    const int rl = lane >> 2;

    const int nwg = gridDim.x;
    int id = blockIdx.x;
    id = (id & 7) * (nwg >> 3) + (id >> 3);
    const int MT = M >> 8, NTn = N >> 7;
    const int slice = id / (MT * NTn);
    const int r2 = id % (MT * NTn);
    const int m0 = (r2 % MT) << 8;
    const int n0 = (r2 / MT) << 7;
    const int Ks = K / SPLITK;
    const int NT = Ks >> 6;
    const size_t ldb = (size_t)K * 2;

    const char* pa = (const char*)A + (size_t)m0 * ldb + (size_t)slice * Ks * 2;
    const char* pb = (const char*)Bt + (size_t)n0 * ldb + (size_t)slice * Ks * 2;

    f32x4 acc[4][4] = {};

    for (int t = 0; t < NT; ++t) {
        const char* ga = pa + (size_t)t * 128;
        const char* gb = pb + (size_t)t * 128;
#pragma unroll
        for (int i = 0; i < 4; ++i) {          // A: 32 slots / 8 waves
            const int s = wv * 4 + i;
            const int kh = s >> 4, c = s & 15;
            async_copy16(ga + (size_t)(c * 16 + rl) * ldb + kh * 64 + colsw, As + s * 1024);
        }
#pragma unroll
        for (int i = 0; i < 2; ++i) {          // B: 16 slots / 8 waves
            const int s = wv * 2 + i;
            const int kh = s >> 3, c = s & 7;
            async_copy16(gb + (size_t)(c * 16 + rl) * ldb + kh * 64 + colsw, Bs + s * 1024);
        }
        __syncthreads();
#pragma unroll
        for (int kh = 0; kh < 2; ++kh) {
            bf16x8 fa[4], fb[4];
#pragma unroll
            for (int fn = 0; fn < 4; ++fn)
                fb[fn] = *(const bf16x8*)(Bs + (kh * 8 + wc * 4 + fn) * 1024 + rdoff);
#pragma unroll
            for (int fm = 0; fm < 4; ++fm)
                fa[fm] = *(const bf16x8*)(As + (kh * 16 + wr * 4 + fm) * 1024 + rdoff);
#pragma unroll
            for (int fm = 0; fm < 4; ++fm)
#pragma unroll
                for (int fn = 0; fn < 4; ++fn)
                    acc[fm][fn] = __builtin_amdgcn_mfma_f32_16x16x32_bf16(fa[fm], fb[fn],
                                                                          acc[fm][fn], 0, 0, 0);
        }
        __syncthreads();
    }

#pragma unroll
    for (int fm = 0; fm < 4; ++fm) {
#pragma unroll
        for (int fn = 0; fn < 4; ++fn) {
            const int mrow = m0 + wr * 64 + fm * 16 + g * 4;
            const int ncol = n0 + wc * 64 + fn * 16 + qq;
            if constexpr (EPI == 2) {
                const float bs = bias[ncol];
                u16* dst = (u16*)out0;
#pragma unroll
                for (int r = 0; r < 4; ++r)
                    dst[(size_t)(mrow + r) * N + ncol] = f2bf(gelu_f(acc[fm][fn][r] + bs));
            } else {  // EPI 4: raw f32 partial
                float* dst = (float*)out0 + (size_t)slice * M * N;
#pragma unroll
                for (int r = 0; r < 4; ++r)
                    dst[(size_t)(mrow + r) * N + ncol] = acc[fm][fn][r];
            }
        }
    }
}

// split-K reduce + bias + residual -> f32 out
template <int SPLIT>
__global__ __launch_bounds__(256) void reduceN_kernel(const float* __restrict__ p,
                                                      const float* __restrict__ bias,
                                                      const float* __restrict__ res,
                                                      float* __restrict__ out,
                                                      int MN4, int N4) {
    const int i = blockIdx.x * 256 + threadIdx.x;   // one float4
    float4 s = ((const float4*)p)[i];
#pragma unroll
    for (int s2 = 1; s2 < SPLIT; ++s2) {
        const float4 q = ((const float4*)p)[(size_t)s2 * MN4 + i];
        s.x += q.x; s.y += q.y; s.z += q.z; s.w += q.w;
    }
    const float4 r = ((const float4*)res)[i];
    const float4 bs = ((const float4*)bias)[i & (N4 - 1)];
    float4 o;
    o.x = s.x + r.x + bs.x;
    o.y = s.y + r.y + bs.y;
    o.z = s.z + r.z + bs.z;
    o.w = s.w + r.w + bs.w;
    ((float4*)out)[i] = o;
}

// ---------------- causal flash attention v6: 4-way KV-segment split ----------------
// Grid (16 qchunks reversed, 4 segments, 32 bh) = 2048 blocks; longest chain 8 tiles.
// Single-buffered K/V (LDS 33.8 KB -> 4 blocks/CU). Empty segments write (m=-60000,l=0,O=0),
// zero-weight in the 4-way combine. Math identical to rounds 9/10 (passed).
DEVI void stage_kv(const char* kbase, const char* vbase, int key0,
                   u16* ksm, u16* vsm, int wv, int lane) {
#pragma unroll
    for (int i = 0; i < 2; ++i) {
        const int c = wv + i * 4;
        const int off = c * 1024 + lane * 16;
        const int row = off >> 7;
        const int scol = (off & 127) ^ ((row & 7) << 4);
        async_copy16(kbase + (size_t)key0 * 128 + (size_t)row * 128 + scol,
                     (char*)ksm + c * 1024);
    }
#pragma unroll
    for (int i = 0; i < 2; ++i) {
        const int c = wv + i * 4;
        const int row = c * 8 + (lane >> 3);
        const int scol = ((lane & 7) * 16) ^ ((row & 7) << 4);
        async_copy16(vbase + (size_t)row * 4096 + (size_t)key0 * 2 + scol,
                     (char*)vsm + c * 1024);
    }
}

__global__ __launch_bounds__(256, 4) void attn32_seg(const u16* __restrict__ Q,
                                                     const u16* __restrict__ Kk,
                                                     const u16* __restrict__ Vt,
                                                     float* __restrict__ opart,
                                                     float2* __restrict__ ml) {
    const int bh = blockIdx.z;
    const int seg = blockIdx.y;
    const int qb = gridDim.x - 1 - blockIdx.x;   // reversed: longest chains dispatch first
    const int tid = threadIdx.x;
    const int wv = tid >> 6, lane = tid & 63;
    const int hi = lane >> 5, qc = lane & 31;

    __shared__ __align__(16) u16 Ksm[4096];
    __shared__ __align__(16) u16 Vsm[4096];
    __shared__ __align__(16) u16 Pl[4][32 * 68];   // per-wave P[q][key], stride 68 u16 (2-way)

    const char* Kb = (const char*)(Kk + (size_t)bh * 2048 * 64);
    const char* Vb = (const char*)(Vt + (size_t)bh * 64 * 2048);
    u16* Pw = &Pl[wv][0];

    const int q0w = qb * 128 + wv * 32;
    const int qg = q0w + qc;
    const int T = 2 * qb + 2;
    const int kt_begin = (seg * T) >> 2;
    const int kt_end = ((seg + 1) * T) >> 2;
    const int ntw = min(kt_end, 2 * qb + (wv >> 1) + 1);   // per-wave causal clamp

    bf16x8 qf[4];
    {
        const u16* Qp = Q + ((size_t)bh * 2048 + qg) * 64;
#pragma unroll
        for (int c = 0; c < 4; ++c)
            qf[c] = *(const bf16x8*)(Qp + c * 16 + hi * 8);
    }

    f32x16 oacc[2];
#pragma unroll
    for (int r = 0; r < 16; ++r) { oacc[0][r] = 0.0f; oacc[1][r] = 0.0f; }
    float m_run = -60000.0f, l_run = 0.0f;

    for (int kt = kt_begin; kt < kt_end; ++kt) {
        const int key0 = kt * 64;
        stage_kv(Kb, Vb, key0, Ksm, Vsm, wv, lane);
        __syncthreads();
        if (kt < ntw) {
            // S^T = K * Q^T
            f32x16 sacc[2];
#pragma unroll
            for (int r = 0; r < 16; ++r) { sacc[0][r] = 0.0f; sacc[1][r] = 0.0f; }
#pragma unroll
            for (int c = 0; c < 4; ++c) {
#pragma unroll
                for (int kb = 0; kb < 2; ++kb) {
                    const int kr = kb * 32 + qc;
                    const bf16x8 ak = *(const bf16x8*)((const char*)Ksm + kr * 128 +
                                          ((c * 32 + hi * 16) ^ ((kr & 7) << 4)));
                    sacc[kb] = __builtin_amdgcn_mfma_f32_32x32x16_bf16(ak, qf[c],
                                                                       sacc[kb], 0, 0, 0);
                }
            }
            // causal mask (only tiles crossing the diagonal) + row max
            float pmax = -1e30f;
            if (key0 + 63 > q0w) {
#pragma unroll
                for (int kb = 0; kb < 2; ++kb)
#pragma unroll
                    for (int r = 0; r < 16; ++r) {
                        const int key = key0 + kb * 32 + (r & 3) + 8 * (r >> 2) + 4 * hi;
                        float s = sacc[kb][r];
                        if (key > qg) s = -1e30f;
                        sacc[kb][r] = s;
                        pmax = fmaxf(pmax, s);
                    }
            } else {
#pragma unroll
                for (int kb = 0; kb < 2; ++kb)
#pragma unroll
                    for (int r = 0; r < 16; ++r) pmax = fmaxf(pmax, sacc[kb][r]);
            }
            pmax = fmaxf(pmax, __shfl_xor(pmax, 32));
            if (pmax > m_run + 11.0f) {          // defer-max: skip rescale when close
                const float alpha = __builtin_amdgcn_exp2f(m_run - pmax);
#pragma unroll
                for (int r = 0; r < 16; ++r) { oacc[0][r] *= alpha; oacc[1][r] *= alpha; }
                l_run *= alpha;
                m_run = pmax;
            }
            float lsum = 0.0f;
#pragma unroll
            for (int kb = 0; kb < 2; ++kb)
#pragma unroll
                for (int j = 0; j < 4; ++j) {
                    u16x4 pk4;
#pragma unroll
                    for (int t = 0; t < 4; ++t) {
                        const float e = __builtin_amdgcn_exp2f(sacc[kb][j * 4 + t] - m_run);
                        lsum += e;
                        pk4[t] = f2bf(e);
                    }
                    *(u16x4*)(Pw + qc * 68 + kb * 32 + j * 8 + 4 * hi) = pk4;
                }
            lsum += __shfl_xor(lsum, 32);
            l_run += lsum;
            // O^T += V^T * P  (P read as two 8B bf16x4 loads: 2-way banks)
#pragma unroll
            for (int c = 0; c < 4; ++c) {
                const u16* pp = Pw + qc * 68 + c * 16 + hi * 8;
                union { bf16x8 v; struct { bf16x4 lo; bf16x4 hi2; } s; } u;
                u.s.lo  = *(const bf16x4*)(pp);
                u.s.hi2 = *(const bf16x4*)(pp + 4);
                const bf16x8 pf = u.v;
#pragma unroll
                for (int db = 0; db < 2; ++db) {
                    const int dr = db * 32 + qc;
                    const bf16x8 av = *(const bf16x8*)((const char*)Vsm + dr * 128 +
                                          ((c * 32 + hi * 16) ^ ((dr & 7) << 4)));
                    oacc[db] = __builtin_amdgcn_mfma_f32_32x32x16_bf16(av, pf,
                                                                       oacc[db], 0, 0, 0);
                }
            }
        }
        __syncthreads();
    }

    // write unnormalized partial O (f32) + (m,l)
    const size_t row = (size_t)seg * 65536 + (size_t)bh * 2048 + qg;
    float* op = opart + row * 64;
#pragma unroll
    for (int db = 0; db < 2; ++db)
#pragma unroll
        for (int j = 0; j < 4; ++j) {
            float4 v;
            v.x = oacc[db][j * 4 + 0];
            v.y = oacc[db][j * 4 + 1];
            v.z = oacc[db][j * 4 + 2];
            v.w = oacc[db][j * 4 + 3];
            *(float4*)(op + db * 32 + j * 8 + 4 * hi) = v;
        }
    if (hi == 0) { float2 t; t.x = m_run; t.y = l_run; ml[row] = t; }
}

// merge 4 segments -> Y bf16 [4096][1024]
__global__ __launch_bounds__(256) void attn_comb4(const float* __restrict__ opart,
                                                  const float2* __restrict__ ml,
                                                  u16* __restrict__ Y) {
    const int idx = blockIdx.x * 256 + threadIdx.x;   // one float4 of d
    const int row = idx >> 4, d4 = idx & 15;
    float2 m_l[4];
#pragma unroll
    for (int s = 0; s < 4; ++s) m_l[s] = ml[(size_t)s * 65536 + row];
    float m = fmaxf(fmaxf(m_l[0].x, m_l[1].x), fmaxf(m_l[2].x, m_l[3].x));
    float w[4], lsum = 0.0f;
#pragma unroll
    for (int s = 0; s < 4; ++s) { w[s] = __builtin_amdgcn_exp2f(m_l[s].x - m); lsum += m_l[s].y * w[s]; }
    const float inv = 1.0f / lsum;
    float4 acc = {0.0f, 0.0f, 0.0f, 0.0f};
#pragma unroll
    for (int s = 0; s < 4; ++s) {
        const float4 a = ((const float4*)opart)[((size_t)s * 65536 + row) * 16 + d4];
        acc.x += a.x * w[s]; acc.y += a.y * w[s]; acc.z += a.z * w[s]; acc.w += a.w * w[s];
    }
    const int bh = row >> 11, q = row & 2047;
    const int b_ = bh >> 4, hh = bh & 15;
    u16x4 o;
    o[0] = f2bf(acc.x * inv);
    o[1] = f2bf(acc.y * inv);
    o[2] = f2bf(acc.z * inv);
    o[3] = f2bf(acc.w * inv);
    *(u16x4*)(Y + ((size_t)(b_ * 2048 + q)) * 1024 + hh * 64 + d4 * 4) = o;
}

// ---------------- host ----------------
extern "C" void kernel_launch(void* const* d_in, const int* in_sizes, int n_in,
                              void* d_out, int out_size, void* d_ws, size_t ws_size,
                              hipStream_t stream) {
    (void)in_sizes; (void)n_in; (void)out_size;
    const float* x      = (const float*)d_in[0];
    const float* w_qkv  = (const float*)d_in[2];
    const float* b_qkv  = (const float*)d_in[3];
    const float* w_proj = (const float*)d_in[4];
    const float* b_proj = (const float*)d_in[5];
    const float* w_fc1  = (const float*)d_in[6];
    const float* b_fc1  = (const float*)d_in[7];
    const float* w_fc2  = (const float*)d_in[8];
    const float* b_fc2  = (const float*)d_in[9];
    const float* g1     = (const float*)d_in[10];
    const float* be1    = (const float*)d_in[11];
    const float* g2     = (const float*)d_in[12];
    const float* be2    = (const float*)d_in[13];

    char* ws = (char*)d_ws;
    size_t off = 0;
    auto alloc = [&](size_t bytes) { size_t r = off; off += (bytes + 255) & ~(size_t)255; return r; };
    u16*   wt_qkv = (u16*)(ws + alloc((size_t)3072 * 1024 * 2));
    u16*   wt_prj = (u16*)(ws + alloc((size_t)1024 * 1024 * 2));
    u16*   wt_fc1 = (u16*)(ws + alloc((size_t)4096 * 1024 * 2));
    u16*   wt_fc2 = (u16*)(ws + alloc((size_t)1024 * 4096 * 2));
    u16*   hbuf   = (u16*)(ws + alloc((size_t)4096 * 1024 * 2));
    float* x1     = (float*)(ws + alloc((size_t)4096 * 1024 * 4));
    char*  big    = ws + alloc((size_t)33554432);
    u16* qb  = (u16*)(big);
    u16* kb  = (u16*)(big + 8388608);
    u16* vtb = (u16*)(big + 16777216);
    u16* yb  = (u16*)(big + 25165824);
    u16* act = (u16*)(big);
    if (off > ws_size) return;
    // part (split-K partials, 64MB) doubles as attention O-partials (4x16MB) + ml (2MB)
    const size_t part_need = (size_t)4 * 4096 * 1024 * 4 + (size_t)4 * 65536 * 8;
    if ((ws_size - off) < part_need) return;
    float*  part  = (float*)(ws + off);
    float*  opart = part;                                        // 4 x 65536 x 64 f32 = 64MB
    float2* mlp   = (float2*)(ws + off + (size_t)4 * 4096 * 1024 * 4);  // 2MB, past splitK region

    const dim3 blk(256);
    tcvt_kernel<<<dim3(32, 96), blk, 0, stream>>>(w_qkv, wt_qkv, 1024, 3072);
    tcvt_kernel<<<dim3(32, 32), blk, 0, stream>>>(w_proj, wt_prj, 1024, 1024);
    tcvt_kernel<<<dim3(32, 128), blk, 0, stream>>>(w_fc1, wt_fc1, 1024, 4096);
    tcvt_kernel<<<dim3(128, 32), blk, 0, stream>>>(w_fc2, wt_fc2, 4096, 1024);

    ln_kernel<<<dim3(4096), blk, 0, stream>>>(x, g1, be1, hbuf);
    // QKV: grid 32*24 = 768
    gemmv6<0, 1><<<dim3(768), blk, 0, stream>>>(hbuf, wt_qkv, b_qkv,
                                                qb, kb, vtb, 4096, 3072, 1024);
    // attention v6: 4-way KV-segment split (2048 blocks), then 4-way combine
    attn32_seg<<<dim3(16, 4, 32), blk, 0, stream>>>(qb, kb, vtb, opart, mlp);
    attn_comb4<<<dim3(4096), blk, 0, stream>>>(opart, mlp, yb);
    // proj split-K=2: grid 32*8*2 = 512, then reduce(+bias+x) -> x1
    gemmv6<4, 2><<<dim3(512), blk, 0, stream>>>(yb, wt_prj, nullptr,
                                                part, nullptr, nullptr, 4096, 1024, 1024);
    reduceN_kernel<2><<<dim3(4096), blk, 0, stream>>>(part, b_proj, x, x1, 1048576, 256);
    ln_kernel<<<dim3(4096), blk, 0, stream>>>(x1, g2, be2, hbuf);
    // FC1 + GELU: A/B test — 256x128 tile, grid 16*32 = 512, 512 threads
    gemm256<2, 1><<<dim3(512), dim3(512), 0, stream>>>(hbuf, wt_fc1, b_fc1,
                                                       act, 4096, 4096, 1024);
    // FC2 split-K=4 (control, 128x128): grid 32*8*4 = 1024, then reduce(+bias+x1) -> d_out
    gemmv6<4, 4><<<dim3(1024), blk, 0, stream>>>(act, wt_fc2, nullptr,
                                                 part, nullptr, nullptr, 4096, 1024, 4096);
    reduceN_kernel<4><<<dim3(4096), blk, 0, stream>>>(part, b_fc2, x1, (float*)d_out,
                                                      1048576, 256);
}

// Round 12
// 244.470 us; speedup vs baseline: 1.0678x; 1.0678x over previous
//
#include <hip/hip_runtime.h>
#include <hip/hip_bf16.h>
#include <stdint.h>

typedef unsigned short u16;
typedef __attribute__((ext_vector_type(8))) short bf16x8;
typedef __attribute__((ext_vector_type(4))) short bf16x4;
typedef __attribute__((ext_vector_type(4))) float f32x4;
typedef __attribute__((ext_vector_type(16))) float f32x16;
typedef __attribute__((ext_vector_type(4))) unsigned short u16x4;

#define DEVI static __device__ __forceinline__

DEVI u16 f2bf(float f) {
    unsigned int u = __builtin_bit_cast(unsigned int, f);
    return (u16)((u + 0x7fffu + ((u >> 16) & 1u)) >> 16);
}

DEVI float gelu_f(float v) {
    // tanh-form GELU: x * sigmoid(1.5957691(x + 0.044715 x^3)); |err vs exact| <= ~3e-4
    const float z = 1.5957691216f * (v + 0.044715f * v * v * v);
    return v / (1.0f + __expf(-z));
}

DEVI void async_copy16(const void* g, void* l) {
    __builtin_amdgcn_global_load_lds((const __attribute__((address_space(1))) void*)g,
                                     (__attribute__((address_space(3))) void*)l,
                                     16, 0, 0);
}

// ---------------- weight transpose + f32->bf16 convert: src[K][N] -> dst[N][K] ----------------
__global__ __launch_bounds__(256) void tcvt_kernel(const float* __restrict__ src,
                                                   u16* __restrict__ dst,
                                                   int K, int N) {
    __shared__ float tile[32][33];
    const int k0 = blockIdx.x * 32, n0 = blockIdx.y * 32;
    const int t = threadIdx.x;
    const int c = t & 31, r0 = t >> 5;
#pragma unroll
    for (int p = 0; p < 4; ++p) {
        const int r = r0 + p * 8;
        tile[r][c] = src[(size_t)(k0 + r) * N + n0 + c];
    }
    __syncthreads();
#pragma unroll
    for (int p = 0; p < 4; ++p) {
        const int r = r0 + p * 8;
        dst[(size_t)(n0 + r) * K + k0 + c] = f2bf(tile[c][r]);
    }
}

// ---------------- LayerNorm (f32 in) -> bf16 out ----------------
__global__ __launch_bounds__(256) void ln_kernel(const float* __restrict__ x,
                                                 const float* __restrict__ gw,
                                                 const float* __restrict__ bw,
                                                 u16* __restrict__ out) {
    const int row = blockIdx.x;
    const int t = threadIdx.x;
    const float4 v = ((const float4*)(x + (size_t)row * 1024))[t];
    float s  = v.x + v.y + v.z + v.w;
    float ss = v.x * v.x + v.y * v.y + v.z * v.z + v.w * v.w;
#pragma unroll
    for (int off = 32; off > 0; off >>= 1) {
        s  += __shfl_down(s, off);
        ss += __shfl_down(ss, off);
    }
    __shared__ float red[8];
    const int wv = t >> 6;
    if ((t & 63) == 0) { red[wv] = s; red[4 + wv] = ss; }
    __syncthreads();
    if (t == 0) {
        red[0] = red[0] + red[1] + red[2] + red[3];
        red[4] = red[4] + red[5] + red[6] + red[7];
    }
    __syncthreads();
    const float mean = red[0] * (1.0f / 1024.0f);
    const float var  = red[4] * (1.0f / 1024.0f) - mean * mean;
    const float rstd = rsqrtf(var + 1e-5f);
    const float4 gv = ((const float4*)gw)[t];
    const float4 bv = ((const float4*)bw)[t];
    u16x4 o;
    o[0] = f2bf((v.x - mean) * rstd * gv.x + bv.x);
    o[1] = f2bf((v.y - mean) * rstd * gv.y + bv.y);
    o[2] = f2bf((v.z - mean) * rstd * gv.z + bv.z);
    o[3] = f2bf((v.w - mean) * rstd * gv.w + bv.w);
    ((u16x4*)out)[(size_t)row * 256 + t] = o;
}

// ================= 128x128 GEMM, BK=64, single-buffer, m97-pure schedule =================
DEVI void stage64(const char* g, size_t ldb, char* lds0, int lane, int wv) {
    const int colsw = ((lane & 3) << 4) ^ (lane & 32);  // inverse-swizzled source col bytes
    const int rl = lane >> 2;
#pragma unroll
    for (int i = 0; i < 4; ++i) {
        const int s = wv * 4 + i;            // slot 0..15
        const int kh = s >> 3, c = s & 7;    // k-half, 16-row subtile
        async_copy16(g + (size_t)(c * 16 + rl) * ldb + kh * 64 + colsw,
                     lds0 + s * 1024);
    }
}

// EPI 0: QKV scatter. EPI 2: gelu->bf16. EPI 4: f32 partial (split-K).
template <int EPI, int SPLITK>
__global__ __launch_bounds__(256, 4) void gemmv6(const u16* __restrict__ A,
                                                 const u16* __restrict__ Bt,
                                                 const float* __restrict__ bias,
                                                 void* __restrict__ out0,
                                                 void* __restrict__ out1,
                                                 void* __restrict__ out2,
                                                 int M, int N, int K) {
    __shared__ __align__(16) char As[16384];
    __shared__ __align__(16) char Bs[16384];
    const int tid = threadIdx.x;
    const int lane = tid & 63, wv = tid >> 6;
    const int wr = wv >> 1, wc = wv & 1;        // 2M x 2N waves, 64x64 each
    const int g = lane >> 4, qq = lane & 15;
    const int rdoff = qq * 64 + ((g * 16) ^ ((qq & 8) << 2));  // swizzled read offset

    const int nwg = gridDim.x;
    int id = blockIdx.x;
    id = (id & 7) * (nwg >> 3) + (id >> 3);
    const int MT = M >> 7, NTn = N >> 7;
    const int slice = id / (MT * NTn);
    const int r2 = id % (MT * NTn);
    const int m0 = (r2 % MT) << 7;
    const int n0 = (r2 / MT) << 7;
    const int Ks = K / SPLITK;
    const int NT = Ks >> 6;
    const size_t ldb = (size_t)K * 2;

    const char* pa = (const char*)A + (size_t)m0 * ldb + (size_t)slice * Ks * 2;
    const char* pb = (const char*)Bt + (size_t)n0 * ldb + (size_t)slice * Ks * 2;

    f32x4 acc[4][4] = {};

    for (int t = 0; t < NT; ++t) {
        stage64(pa + (size_t)t * 128, ldb, As, lane, wv);
        stage64(pb + (size_t)t * 128, ldb, Bs, lane, wv);
        __syncthreads();
#pragma unroll
        for (int kh = 0; kh < 2; ++kh) {
            bf16x8 fa[4], fb[4];
#pragma unroll
            for (int fn = 0; fn < 4; ++fn)
                fb[fn] = *(const bf16x8*)(Bs + (kh * 8 + wc * 4 + fn) * 1024 + rdoff);
#pragma unroll
            for (int fm = 0; fm < 4; ++fm)
                fa[fm] = *(const bf16x8*)(As + (kh * 8 + wr * 4 + fm) * 1024 + rdoff);
#pragma unroll
            for (int fm = 0; fm < 4; ++fm)
#pragma unroll
                for (int fn = 0; fn < 4; ++fn)
                    acc[fm][fn] = __builtin_amdgcn_mfma_f32_16x16x32_bf16(fa[fm], fb[fn],
                                                                          acc[fm][fn], 0, 0, 0);
        }
        __syncthreads();
    }

#pragma unroll
    for (int fm = 0; fm < 4; ++fm) {
#pragma unroll
        for (int fn = 0; fn < 4; ++fn) {
            const int mrow = m0 + wr * 64 + fm * 16 + g * 4;
            const int ncol = n0 + wc * 64 + fn * 16 + qq;
            if constexpr (EPI == 0) {
                const float bs = bias[ncol];
                const int sec = ncol >> 10;
                const int hd_ = ncol & 1023;
                const int hh = hd_ >> 6, dd = hd_ & 63;
                if (sec == 2) {
                    const int b_ = mrow >> 11, l_ = mrow & 2047;
                    u16x4 pk;
#pragma unroll
                    for (int r = 0; r < 4; ++r) pk[r] = f2bf(acc[fm][fn][r] + bs);
                    *(u16x4*)((u16*)out2 + ((size_t)((b_ * 16 + hh) * 64 + dd)) * 2048 + l_) = pk;
                } else {
                    u16* dst = (sec == 0) ? (u16*)out0 : (u16*)out1;
                    // q-scale folds softmax 1/sqrt(hd) AND log2(e) for exp2-domain softmax
                    const float sc = (sec == 0) ? 0.1803368801f : 1.0f;
#pragma unroll
                    for (int r = 0; r < 4; ++r) {
                        const int mr = mrow + r;
                        const int b_ = mr >> 11, l_ = mr & 2047;
                        dst[((size_t)((b_ * 16 + hh) * 2048 + l_)) * 64 + dd] =
                            f2bf((acc[fm][fn][r] + bs) * sc);
                    }
                }
            } else if constexpr (EPI == 2) {
                const float bs = bias[ncol];
                u16* dst = (u16*)out0;
#pragma unroll
                for (int r = 0; r < 4; ++r)
                    dst[(size_t)(mrow + r) * N + ncol] = f2bf(gelu_f(acc[fm][fn][r] + bs));
            } else {  // EPI 4: raw f32 partial for split-K
                float* dst = (float*)out0 + (size_t)slice * M * N;
#pragma unroll
                for (int r = 0; r < 4; ++r)
                    dst[(size_t)(mrow + r) * N + ncol] = acc[fm][fn][r];
            }
        }
    }
}

// split-K reduce + bias + residual -> f32 out (final FC2 path)
template <int SPLIT>
__global__ __launch_bounds__(256) void reduceN_kernel(const float* __restrict__ p,
                                                      const float* __restrict__ bias,
                                                      const float* __restrict__ res,
                                                      float* __restrict__ out,
                                                      int MN4, int N4) {
    const int i = blockIdx.x * 256 + threadIdx.x;   // one float4
    float4 s = ((const float4*)p)[i];
#pragma unroll
    for (int s2 = 1; s2 < SPLIT; ++s2) {
        const float4 q = ((const float4*)p)[(size_t)s2 * MN4 + i];
        s.x += q.x; s.y += q.y; s.z += q.z; s.w += q.w;
    }
    const float4 r = ((const float4*)res)[i];
    const float4 bs = ((const float4*)bias)[i & (N4 - 1)];
    float4 o;
    o.x = s.x + r.x + bs.x;
    o.y = s.y + r.y + bs.y;
    o.z = s.z + r.z + bs.z;
    o.w = s.w + r.w + bs.w;
    ((float4*)out)[i] = o;
}

// split-K reduce + bias + residual + LayerNorm fused (proj path):
// one block per row (1024 floats = 256 float4). Writes x1 (f32) AND ln(x1) (bf16).
template <int SPLIT>
__global__ __launch_bounds__(256) void reduceLN_kernel(const float* __restrict__ p,
                                                       const float* __restrict__ bias,
                                                       const float* __restrict__ res,
                                                       const float* __restrict__ gw,
                                                       const float* __restrict__ bw,
                                                       float* __restrict__ xout,
                                                       u16* __restrict__ lnout,
                                                       int MN4) {
    const int row = blockIdx.x;
    const int t = threadIdx.x;
    const int i = row * 256 + t;
    float4 s = ((const float4*)p)[i];
#pragma unroll
    for (int s2 = 1; s2 < SPLIT; ++s2) {
        const float4 q = ((const float4*)p)[(size_t)s2 * MN4 + i];
        s.x += q.x; s.y += q.y; s.z += q.z; s.w += q.w;
    }
    const float4 r = ((const float4*)res)[i];
    const float4 bs = ((const float4*)bias)[t];
    float4 o;
    o.x = s.x + r.x + bs.x;
    o.y = s.y + r.y + bs.y;
    o.z = s.z + r.z + bs.z;
    o.w = s.w + r.w + bs.w;
    ((float4*)xout)[i] = o;
    // LayerNorm over the row
    float sum  = o.x + o.y + o.z + o.w;
    float ssum = o.x * o.x + o.y * o.y + o.z * o.z + o.w * o.w;
#pragma unroll
    for (int off = 32; off > 0; off >>= 1) {
        sum  += __shfl_down(sum, off);
        ssum += __shfl_down(ssum, off);
    }
    __shared__ float red[8];
    const int wv = t >> 6;
    if ((t & 63) == 0) { red[wv] = sum; red[4 + wv] = ssum; }
    __syncthreads();
    if (t == 0) {
        red[0] = red[0] + red[1] + red[2] + red[3];
        red[4] = red[4] + red[5] + red[6] + red[7];
    }
    __syncthreads();
    const float mean = red[0] * (1.0f / 1024.0f);
    const float var  = red[4] * (1.0f / 1024.0f) - mean * mean;
    const float rstd = rsqrtf(var + 1e-5f);
    const float4 gv = ((const float4*)gw)[t];
    const float4 bv = ((const float4*)bw)[t];
    u16x4 ov;
    ov[0] = f2bf((o.x - mean) * rstd * gv.x + bv.x);
    ov[1] = f2bf((o.y - mean) * rstd * gv.y + bv.y);
    ov[2] = f2bf((o.z - mean) * rstd * gv.z + bv.z);
    ov[3] = f2bf((o.w - mean) * rstd * gv.w + bv.w);
    ((u16x4*)lnout)[(size_t)row * 256 + t] = ov;
}

// ---------------- causal flash attention (R7 paired kernel + P-stride-68 bank fix) ----------
// Block = 4 waves x 32 q-rows; triangle-paired: block bx does q-chunk (15-bx) then bx ->
// uniform 36 KV-tiles. Double-buffered K/V (needed: 1 block/CU, no cross-block TLP).
// Swapped S^T = K*Q^T; exp2-domain softmax; defer-max THR=11; P stride 68 u16 (2-way banks).
DEVI void stage_kv2(const char* kbase, const char* vbase, int key0,
                    u16* ksm, u16* vsm, int wv, int lane) {
#pragma unroll
    for (int i = 0; i < 2; ++i) {
        const int c = wv + i * 4;
        const int off = c * 1024 + lane * 16;
        const int row = off >> 7;
        const int scol = (off & 127) ^ ((row & 7) << 4);
        async_copy16(kbase + (size_t)key0 * 128 + (size_t)row * 128 + scol,
                     (char*)ksm + c * 1024);
    }
#pragma unroll
    for (int i = 0; i < 2; ++i) {
        const int c = wv + i * 4;
        const int row = c * 8 + (lane >> 3);
        const int scol = ((lane & 7) * 16) ^ ((row & 7) << 4);
        async_copy16(vbase + (size_t)row * 4096 + (size_t)key0 * 2 + scol,
                     (char*)vsm + c * 1024);
    }
}

__global__ __launch_bounds__(256, 3) void attn32_kernel(const u16* __restrict__ Q,
                                                        const u16* __restrict__ Kk,
                                                        const u16* __restrict__ Vt,
                                                        u16* __restrict__ Y) {
    const int bh = blockIdx.y;
    const int b_ = bh >> 4, hh = bh & 15;
    const int bx = blockIdx.x;                 // 0..7
    const int tid = threadIdx.x;
    const int wv = tid >> 6, lane = tid & 63;
    const int hi = lane >> 5, qc = lane & 31;

    __shared__ __align__(16) u16 Ksm[2][4096];
    __shared__ __align__(16) u16 Vsm[2][4096];
    __shared__ __align__(16) u16 Pl[4][32 * 68];   // per-wave P[q][key], stride 68 u16

    const char* Kb = (const char*)(Kk + (size_t)bh * 2048 * 64);
    const char* Vb = (const char*)(Vt + (size_t)bh * 64 * 2048);
    u16* Pw = &Pl[wv][0];

#pragma unroll 1
    for (int part = 0; part < 2; ++part) {
        const int qb = part ? bx : (15 - bx);    // large chunk first
        const int q0w = qb * 128 + wv * 32;
        const int qg = q0w + qc;
        const int ntile = qb * 2 + 2;
        const int ntile_w = qb * 2 + (wv >> 1) + 1;   // per-wave causal clamp

        bf16x8 qf[4];
        {
            const u16* Qp = Q + ((size_t)bh * 2048 + qg) * 64;
#pragma unroll
            for (int c = 0; c < 4; ++c)
                qf[c] = *(const bf16x8*)(Qp + c * 16 + hi * 8);
        }

        f32x16 oacc[2];
#pragma unroll
        for (int r = 0; r < 16; ++r) { oacc[0][r] = 0.0f; oacc[1][r] = 0.0f; }
        float m_run = -60000.0f, l_run = 0.0f;

        stage_kv2(Kb, Vb, 0, Ksm[0], Vsm[0], wv, lane);
        __syncthreads();
        int cur = 0;
        for (int kt = 0; kt < ntile; ++kt) {
            const int key0 = kt * 64;
            if (kt + 1 < ntile)
                stage_kv2(Kb, Vb, key0 + 64, Ksm[cur ^ 1], Vsm[cur ^ 1], wv, lane);
            if (kt < ntile_w) {
                // S^T = K * Q^T
                f32x16 sacc[2];
#pragma unroll
                for (int r = 0; r < 16; ++r) { sacc[0][r] = 0.0f; sacc[1][r] = 0.0f; }
#pragma unroll
                for (int c = 0; c < 4; ++c) {
#pragma unroll
                    for (int kb = 0; kb < 2; ++kb) {
                        const int kr = kb * 32 + qc;
                        const bf16x8 ak = *(const bf16x8*)((const char*)Ksm[cur] + kr * 128 +
                                              ((c * 32 + hi * 16) ^ ((kr & 7) << 4)));
                        sacc[kb] = __builtin_amdgcn_mfma_f32_32x32x16_bf16(ak, qf[c],
                                                                           sacc[kb], 0, 0, 0);
                    }
                }
                float pmax = -1e30f;
                if (key0 + 63 > q0w) {
#pragma unroll
                    for (int kb = 0; kb < 2; ++kb)
#pragma unroll
                        for (int r = 0; r < 16; ++r) {
                            const int key = key0 + kb * 32 + (r & 3) + 8 * (r >> 2) + 4 * hi;
                            float s = sacc[kb][r];
                            if (key > qg) s = -1e30f;
                            sacc[kb][r] = s;
                            pmax = fmaxf(pmax, s);
                        }
                } else {
#pragma unroll
                    for (int kb = 0; kb < 2; ++kb)
#pragma unroll
                        for (int r = 0; r < 16; ++r) pmax = fmaxf(pmax, sacc[kb][r]);
                }
                pmax = fmaxf(pmax, __shfl_xor(pmax, 32));
                if (pmax > m_run + 11.0f) {          // defer-max
                    const float alpha = __builtin_amdgcn_exp2f(m_run - pmax);
#pragma unroll
                    for (int r = 0; r < 16; ++r) { oacc[0][r] *= alpha; oacc[1][r] *= alpha; }
                    l_run *= alpha;
                    m_run = pmax;
                }
                float lsum = 0.0f;
#pragma unroll
                for (int kb = 0; kb < 2; ++kb)
#pragma unroll
                    for (int j = 0; j < 4; ++j) {
                        u16x4 pk4;
#pragma unroll
                        for (int t = 0; t < 4; ++t) {
                            const float e = __builtin_amdgcn_exp2f(sacc[kb][j * 4 + t] - m_run);
                            lsum += e;
                            pk4[t] = f2bf(e);
                        }
                        *(u16x4*)(Pw + qc * 68 + kb * 32 + j * 8 + 4 * hi) = pk4;
                    }
                lsum += __shfl_xor(lsum, 32);
                l_run += lsum;
                // O^T += V^T * P  (P read as two 8B bf16x4 loads: 2-way banks)
#pragma unroll
                for (int c = 0; c < 4; ++c) {
                    const u16* pp = Pw + qc * 68 + c * 16 + hi * 8;
                    union { bf16x8 v; struct { bf16x4 lo; bf16x4 hi2; } s; } u;
                    u.s.lo  = *(const bf16x4*)(pp);
                    u.s.hi2 = *(const bf16x4*)(pp + 4);
                    const bf16x8 pf = u.v;
#pragma unroll
                    for (int db = 0; db < 2; ++db) {
                        const int dr = db * 32 + qc;
                        const bf16x8 av = *(const bf16x8*)((const char*)Vsm[cur] + dr * 128 +
                                              ((c * 32 + hi * 16) ^ ((dr & 7) << 4)));
                        oacc[db] = __builtin_amdgcn_mfma_f32_32x32x16_bf16(av, pf,
                                                                           oacc[db], 0, 0, 0);
                    }
                }
            }
            __syncthreads();
            cur ^= 1;
        }
        const float inv = 1.0f / l_run;
        u16* Yp = &Y[((size_t)(b_ * 2048 + qg)) * 1024 + hh * 64];
#pragma unroll
        for (int db = 0; db < 2; ++db)
#pragma unroll
            for (int j = 0; j < 4; ++j) {
                u16x4 o;
#pragma unroll
                for (int t = 0; t < 4; ++t) o[t] = f2bf(oacc[db][j * 4 + t] * inv);
                *(u16x4*)(Yp + db * 32 + j * 8 + 4 * hi) = o;
            }
    }
}

// ---------------- host ----------------
extern "C" void kernel_launch(void* const* d_in, const int* in_sizes, int n_in,
                              void* d_out, int out_size, void* d_ws, size_t ws_size,
                              hipStream_t stream) {
    (void)in_sizes; (void)n_in; (void)out_size;
    const float* x      = (const float*)d_in[0];
    const float* w_qkv  = (const float*)d_in[2];
    const float* b_qkv  = (const float*)d_in[3];
    const float* w_proj = (const float*)d_in[4];
    const float* b_proj = (const float*)d_in[5];
    const float* w_fc1  = (const float*)d_in[6];
    const float* b_fc1  = (const float*)d_in[7];
    const float* w_fc2  = (const float*)d_in[8];
    const float* b_fc2  = (const float*)d_in[9];
    const float* g1     = (const float*)d_in[10];
    const float* be1    = (const float*)d_in[11];
    const float* g2     = (const float*)d_in[12];
    const float* be2    = (const float*)d_in[13];

    char* ws = (char*)d_ws;
    size_t off = 0;
    auto alloc = [&](size_t bytes) { size_t r = off; off += (bytes + 255) & ~(size_t)255; return r; };
    u16*   wt_qkv = (u16*)(ws + alloc((size_t)3072 * 1024 * 2));
    u16*   wt_prj = (u16*)(ws + alloc((size_t)1024 * 1024 * 2));
    u16*   wt_fc1 = (u16*)(ws + alloc((size_t)4096 * 1024 * 2));
    u16*   wt_fc2 = (u16*)(ws + alloc((size_t)1024 * 4096 * 2));
    u16*   hbuf   = (u16*)(ws + alloc((size_t)4096 * 1024 * 2));
    float* x1     = (float*)(ws + alloc((size_t)4096 * 1024 * 4));
    char*  big    = ws + alloc((size_t)33554432);
    u16* qb  = (u16*)(big);
    u16* kb  = (u16*)(big + 8388608);
    u16* vtb = (u16*)(big + 16777216);
    u16* yb  = (u16*)(big + 25165824);
    u16* act = (u16*)(big);
    if (off > ws_size) return;
    const size_t part_need = (size_t)4 * 4096 * 1024 * 4;   // splitK partials (proj sK2, FC2 sK4)
    if ((ws_size - off) < part_need) return;
    float* part = (float*)(ws + off);

    const dim3 blk(256);
    tcvt_kernel<<<dim3(32, 96), blk, 0, stream>>>(w_qkv, wt_qkv, 1024, 3072);
    tcvt_kernel<<<dim3(32, 32), blk, 0, stream>>>(w_proj, wt_prj, 1024, 1024);
    tcvt_kernel<<<dim3(32, 128), blk, 0, stream>>>(w_fc1, wt_fc1, 1024, 4096);
    tcvt_kernel<<<dim3(128, 32), blk, 0, stream>>>(w_fc2, wt_fc2, 4096, 1024);

    ln_kernel<<<dim3(4096), blk, 0, stream>>>(x, g1, be1, hbuf);
    // QKV: grid 32*24 = 768
    gemmv6<0, 1><<<dim3(768), blk, 0, stream>>>(hbuf, wt_qkv, b_qkv,
                                                qb, kb, vtb, 4096, 3072, 1024);
    // attention: paired triangle (R7 structure), 8 x 32 blocks
    attn32_kernel<<<dim3(8, 32), blk, 0, stream>>>(qb, kb, vtb, yb);
    // proj split-K=2: grid 512, then fused reduce(+bias+x residual)+LN2 -> x1, hbuf
    gemmv6<4, 2><<<dim3(512), blk, 0, stream>>>(yb, wt_prj, nullptr,
                                                part, nullptr, nullptr, 4096, 1024, 1024);
    reduceLN_kernel<2><<<dim3(4096), blk, 0, stream>>>(part, b_proj, x, g2, be2,
                                                       x1, hbuf, 1048576);
    // FC1 + GELU: grid 1024
    gemmv6<2, 1><<<dim3(1024), blk, 0, stream>>>(hbuf, wt_fc1, b_fc1,
                                                 act, nullptr, nullptr, 4096, 4096, 1024);
    // FC2 split-K=4: grid 1024, then reduce(+bias+x1) -> d_out
    gemmv6<4, 4><<<dim3(1024), blk, 0, stream>>>(act, wt_fc2, nullptr,
                                                 part, nullptr, nullptr, 4096, 1024, 4096);
    reduceN_kernel<4><<<dim3(4096), blk, 0, stream>>>(part, b_fc2, x1, (float*)d_out,
                                                      1048576, 256);
}

// Round 13
// 240.719 us; speedup vs baseline: 1.0844x; 1.0156x over previous
//
#include <hip/hip_runtime.h>
#include <hip/hip_bf16.h>
#include <stdint.h>

typedef unsigned short u16;
typedef __attribute__((ext_vector_type(8))) short bf16x8;
typedef __attribute__((ext_vector_type(4))) short bf16x4;
typedef __attribute__((ext_vector_type(4))) float f32x4;
typedef __attribute__((ext_vector_type(16))) float f32x16;
typedef __attribute__((ext_vector_type(4))) unsigned short u16x4;

#define DEVI static __device__ __forceinline__

DEVI u16 f2bf(float f) {
    unsigned int u = __builtin_bit_cast(unsigned int, f);
    return (u16)((u + 0x7fffu + ((u >> 16) & 1u)) >> 16);
}

DEVI float gelu_f(float v) {
    // tanh-form GELU: x * sigmoid(1.5957691(x + 0.044715 x^3)); |err vs exact| <= ~3e-4
    const float z = 1.5957691216f * (v + 0.044715f * v * v * v);
    return v / (1.0f + __expf(-z));
}

DEVI void async_copy16(const void* g, void* l) {
    __builtin_amdgcn_global_load_lds((const __attribute__((address_space(1))) void*)g,
                                     (__attribute__((address_space(3))) void*)l,
                                     16, 0, 0);
}

// ---------------- weight transpose + f32->bf16 convert: src[K][N] -> dst[N][K] ----------------
__global__ __launch_bounds__(256) void tcvt_kernel(const float* __restrict__ src,
                                                   u16* __restrict__ dst,
                                                   int K, int N) {
    __shared__ float tile[32][33];
    const int k0 = blockIdx.x * 32, n0 = blockIdx.y * 32;
    const int t = threadIdx.x;
    const int c = t & 31, r0 = t >> 5;
#pragma unroll
    for (int p = 0; p < 4; ++p) {
        const int r = r0 + p * 8;
        tile[r][c] = src[(size_t)(k0 + r) * N + n0 + c];
    }
    __syncthreads();
#pragma unroll
    for (int p = 0; p < 4; ++p) {
        const int r = r0 + p * 8;
        dst[(size_t)(n0 + r) * K + k0 + c] = f2bf(tile[c][r]);
    }
}

// ---------------- LayerNorm (f32 in) -> bf16 out ----------------
__global__ __launch_bounds__(256) void ln_kernel(const float* __restrict__ x,
                                                 const float* __restrict__ gw,
                                                 const float* __restrict__ bw,
                                                 u16* __restrict__ out) {
    const int row = blockIdx.x;
    const int t = threadIdx.x;
    const float4 v = ((const float4*)(x + (size_t)row * 1024))[t];
    float s  = v.x + v.y + v.z + v.w;
    float ss = v.x * v.x + v.y * v.y + v.z * v.z + v.w * v.w;
#pragma unroll
    for (int off = 32; off > 0; off >>= 1) {
        s  += __shfl_down(s, off);
        ss += __shfl_down(ss, off);
    }
    __shared__ float red[8];
    const int wv = t >> 6;
    if ((t & 63) == 0) { red[wv] = s; red[4 + wv] = ss; }
    __syncthreads();
    if (t == 0) {
        red[0] = red[0] + red[1] + red[2] + red[3];
        red[4] = red[4] + red[5] + red[6] + red[7];
    }
    __syncthreads();
    const float mean = red[0] * (1.0f / 1024.0f);
    const float var  = red[4] * (1.0f / 1024.0f) - mean * mean;
    const float rstd = rsqrtf(var + 1e-5f);
    const float4 gv = ((const float4*)gw)[t];
    const float4 bv = ((const float4*)bw)[t];
    u16x4 o;
    o[0] = f2bf((v.x - mean) * rstd * gv.x + bv.x);
    o[1] = f2bf((v.y - mean) * rstd * gv.y + bv.y);
    o[2] = f2bf((v.z - mean) * rstd * gv.z + bv.z);
    o[3] = f2bf((v.w - mean) * rstd * gv.w + bv.w);
    ((u16x4*)out)[(size_t)row * 256 + t] = o;
}

// ================= 128x128 GEMM, BK=64, single-buffer, m97-pure schedule =================
DEVI void stage64(const char* g, size_t ldb, char* lds0, int lane, int wv) {
    const int colsw = ((lane & 3) << 4) ^ (lane & 32);  // inverse-swizzled source col bytes
    const int rl = lane >> 2;
#pragma unroll
    for (int i = 0; i < 4; ++i) {
        const int s = wv * 4 + i;            // slot 0..15
        const int kh = s >> 3, c = s & 7;    // k-half, 16-row subtile
        async_copy16(g + (size_t)(c * 16 + rl) * ldb + kh * 64 + colsw,
                     lds0 + s * 1024);
    }
}

// EPI 0: QKV scatter. EPI 2: gelu->bf16. EPI 4: f32 partial (split-K).
template <int EPI, int SPLITK>
__global__ __launch_bounds__(256, 4) void gemmv6(const u16* __restrict__ A,
                                                 const u16* __restrict__ Bt,
                                                 const float* __restrict__ bias,
                                                 void* __restrict__ out0,
                                                 void* __restrict__ out1,
                                                 void* __restrict__ out2,
                                                 int M, int N, int K) {
    __shared__ __align__(16) char As[16384];
    __shared__ __align__(16) char Bs[16384];
    const int tid = threadIdx.x;
    const int lane = tid & 63, wv = tid >> 6;
    const int wr = wv >> 1, wc = wv & 1;        // 2M x 2N waves, 64x64 each
    const int g = lane >> 4, qq = lane & 15;
    const int rdoff = qq * 64 + ((g * 16) ^ ((qq & 8) << 2));  // swizzled read offset

    const int nwg = gridDim.x;
    int id = blockIdx.x;
    id = (id & 7) * (nwg >> 3) + (id >> 3);
    const int MT = M >> 7, NTn = N >> 7;
    const int slice = id / (MT * NTn);
    const int r2 = id % (MT * NTn);
    const int m0 = (r2 % MT) << 7;
    const int n0 = (r2 / MT) << 7;
    const int Ks = K / SPLITK;
    const int NT = Ks >> 6;
    const size_t ldb = (size_t)K * 2;

    const char* pa = (const char*)A + (size_t)m0 * ldb + (size_t)slice * Ks * 2;
    const char* pb = (const char*)Bt + (size_t)n0 * ldb + (size_t)slice * Ks * 2;

    f32x4 acc[4][4] = {};

    for (int t = 0; t < NT; ++t) {
        stage64(pa + (size_t)t * 128, ldb, As, lane, wv);
        stage64(pb + (size_t)t * 128, ldb, Bs, lane, wv);
        __syncthreads();
#pragma unroll
        for (int kh = 0; kh < 2; ++kh) {
            bf16x8 fa[4], fb[4];
#pragma unroll
            for (int fn = 0; fn < 4; ++fn)
                fb[fn] = *(const bf16x8*)(Bs + (kh * 8 + wc * 4 + fn) * 1024 + rdoff);
#pragma unroll
            for (int fm = 0; fm < 4; ++fm)
                fa[fm] = *(const bf16x8*)(As + (kh * 8 + wr * 4 + fm) * 1024 + rdoff);
#pragma unroll
            for (int fm = 0; fm < 4; ++fm)
#pragma unroll
                for (int fn = 0; fn < 4; ++fn)
                    acc[fm][fn] = __builtin_amdgcn_mfma_f32_16x16x32_bf16(fa[fm], fb[fn],
                                                                          acc[fm][fn], 0, 0, 0);
        }
        __syncthreads();
    }

#pragma unroll
    for (int fm = 0; fm < 4; ++fm) {
#pragma unroll
        for (int fn = 0; fn < 4; ++fn) {
            const int mrow = m0 + wr * 64 + fm * 16 + g * 4;
            const int ncol = n0 + wc * 64 + fn * 16 + qq;
            if constexpr (EPI == 0) {
                const float bs = bias[ncol];
                const int sec = ncol >> 10;
                const int hd_ = ncol & 1023;
                const int hh = hd_ >> 6, dd = hd_ & 63;
                if (sec == 2) {
                    const int b_ = mrow >> 11, l_ = mrow & 2047;
                    u16x4 pk;
#pragma unroll
                    for (int r = 0; r < 4; ++r) pk[r] = f2bf(acc[fm][fn][r] + bs);
                    *(u16x4*)((u16*)out2 + ((size_t)((b_ * 16 + hh) * 64 + dd)) * 2048 + l_) = pk;
                } else {
                    u16* dst = (sec == 0) ? (u16*)out0 : (u16*)out1;
                    // q-scale folds softmax 1/sqrt(hd) AND log2(e) for exp2-domain softmax
                    const float sc = (sec == 0) ? 0.1803368801f : 1.0f;
#pragma unroll
                    for (int r = 0; r < 4; ++r) {
                        const int mr = mrow + r;
                        const int b_ = mr >> 11, l_ = mr & 2047;
                        dst[((size_t)((b_ * 16 + hh) * 2048 + l_)) * 64 + dd] =
                            f2bf((acc[fm][fn][r] + bs) * sc);
                    }
                }
            } else if constexpr (EPI == 2) {
                const float bs = bias[ncol];
                u16* dst = (u16*)out0;
#pragma unroll
                for (int r = 0; r < 4; ++r)
                    dst[(size_t)(mrow + r) * N + ncol] = f2bf(gelu_f(acc[fm][fn][r] + bs));
            } else {  // EPI 4: raw f32 partial for split-K
                float* dst = (float*)out0 + (size_t)slice * M * N;
#pragma unroll
                for (int r = 0; r < 4; ++r)
                    dst[(size_t)(mrow + r) * N + ncol] = acc[fm][fn][r];
            }
        }
    }
}

// split-K reduce + bias + residual -> f32 out (final FC2 path)
template <int SPLIT>
__global__ __launch_bounds__(256) void reduceN_kernel(const float* __restrict__ p,
                                                      const float* __restrict__ bias,
                                                      const float* __restrict__ res,
                                                      float* __restrict__ out,
                                                      int MN4, int N4) {
    const int i = blockIdx.x * 256 + threadIdx.x;   // one float4
    float4 s = ((const float4*)p)[i];
#pragma unroll
    for (int s2 = 1; s2 < SPLIT; ++s2) {
        const float4 q = ((const float4*)p)[(size_t)s2 * MN4 + i];
        s.x += q.x; s.y += q.y; s.z += q.z; s.w += q.w;
    }
    const float4 r = ((const float4*)res)[i];
    const float4 bs = ((const float4*)bias)[i & (N4 - 1)];
    float4 o;
    o.x = s.x + r.x + bs.x;
    o.y = s.y + r.y + bs.y;
    o.z = s.z + r.z + bs.z;
    o.w = s.w + r.w + bs.w;
    ((float4*)out)[i] = o;
}

// split-K reduce + bias + residual + LayerNorm fused (proj path):
// one block per row (1024 floats = 256 float4). Writes x1 (f32) AND ln(x1) (bf16).
template <int SPLIT>
__global__ __launch_bounds__(256) void reduceLN_kernel(const float* __restrict__ p,
                                                       const float* __restrict__ bias,
                                                       const float* __restrict__ res,
                                                       const float* __restrict__ gw,
                                                       const float* __restrict__ bw,
                                                       float* __restrict__ xout,
                                                       u16* __restrict__ lnout,
                                                       int MN4) {
    const int row = blockIdx.x;
    const int t = threadIdx.x;
    const int i = row * 256 + t;
    float4 s = ((const float4*)p)[i];
#pragma unroll
    for (int s2 = 1; s2 < SPLIT; ++s2) {
        const float4 q = ((const float4*)p)[(size_t)s2 * MN4 + i];
        s.x += q.x; s.y += q.y; s.z += q.z; s.w += q.w;
    }
    const float4 r = ((const float4*)res)[i];
    const float4 bs = ((const float4*)bias)[t];
    float4 o;
    o.x = s.x + r.x + bs.x;
    o.y = s.y + r.y + bs.y;
    o.z = s.z + r.z + bs.z;
    o.w = s.w + r.w + bs.w;
    ((float4*)xout)[i] = o;
    // LayerNorm over the row
    float sum  = o.x + o.y + o.z + o.w;
    float ssum = o.x * o.x + o.y * o.y + o.z * o.z + o.w * o.w;
#pragma unroll
    for (int off = 32; off > 0; off >>= 1) {
        sum  += __shfl_down(sum, off);
        ssum += __shfl_down(ssum, off);
    }
    __shared__ float red[8];
    const int wv = t >> 6;
    if ((t & 63) == 0) { red[wv] = sum; red[4 + wv] = ssum; }
    __syncthreads();
    if (t == 0) {
        red[0] = red[0] + red[1] + red[2] + red[3];
        red[4] = red[4] + red[5] + red[6] + red[7];
    }
    __syncthreads();
    const float mean = red[0] * (1.0f / 1024.0f);
    const float var  = red[4] * (1.0f / 1024.0f) - mean * mean;
    const float rstd = rsqrtf(var + 1e-5f);
    const float4 gv = ((const float4*)gw)[t];
    const float4 bv = ((const float4*)bw)[t];
    u16x4 ov;
    ov[0] = f2bf((o.x - mean) * rstd * gv.x + bv.x);
    ov[1] = f2bf((o.y - mean) * rstd * gv.y + bv.y);
    ov[2] = f2bf((o.z - mean) * rstd * gv.z + bv.z);
    ov[3] = f2bf((o.w - mean) * rstd * gv.w + bv.w);
    ((u16x4*)lnout)[(size_t)row * 256 + t] = ov;
}

// ---------------- causal flash attention (paired kernel, XCD-grouped 1D grid) ----------
// Grid = 256 blocks 1D: bh = id & 31, bx = id >> 5. XCD = linear_id % 8 = bh % 8, so all
// 8 blocks sharing one bh's K/V (512 KB) land on ONE XCD -> K/V becomes L2-resident
// (4 bh x 512 KB = 2 MB per 4 MB XCD-L2) instead of 8x-duplicated across XCDs.
// Block = 4 waves x 32 q-rows; triangle-paired: chunk (15-bx) then bx -> uniform 36 tiles.
// Swapped S^T = K*Q^T; exp2-domain softmax; defer-max THR=11; P stride 68 u16.
DEVI void stage_kv2(const char* kbase, const char* vbase, int key0,
                    u16* ksm, u16* vsm, int wv, int lane) {
#pragma unroll
    for (int i = 0; i < 2; ++i) {
        const int c = wv + i * 4;
        const int off = c * 1024 + lane * 16;
        const int row = off >> 7;
        const int scol = (off & 127) ^ ((row & 7) << 4);
        async_copy16(kbase + (size_t)key0 * 128 + (size_t)row * 128 + scol,
                     (char*)ksm + c * 1024);
    }
#pragma unroll
    for (int i = 0; i < 2; ++i) {
        const int c = wv + i * 4;
        const int row = c * 8 + (lane >> 3);
        const int scol = ((lane & 7) * 16) ^ ((row & 7) << 4);
        async_copy16(vbase + (size_t)row * 4096 + (size_t)key0 * 2 + scol,
                     (char*)vsm + c * 1024);
    }
}

__global__ __launch_bounds__(256, 3) void attn32_kernel(const u16* __restrict__ Q,
                                                        const u16* __restrict__ Kk,
                                                        const u16* __restrict__ Vt,
                                                        u16* __restrict__ Y) {
    const int id = blockIdx.x;
    const int bh = id & 31;                    // XCD = id % 8 = bh % 8 -> K/V L2-resident
    const int bx = id >> 5;                    // 0..7
    const int b_ = bh >> 4, hh = bh & 15;
    const int tid = threadIdx.x;
    const int wv = tid >> 6, lane = tid & 63;
    const int hi = lane >> 5, qc = lane & 31;

    __shared__ __align__(16) u16 Ksm[2][4096];
    __shared__ __align__(16) u16 Vsm[2][4096];
    __shared__ __align__(16) u16 Pl[4][32 * 68];   // per-wave P[q][key], stride 68 u16

    const char* Kb = (const char*)(Kk + (size_t)bh * 2048 * 64);
    const char* Vb = (const char*)(Vt + (size_t)bh * 64 * 2048);
    u16* Pw = &Pl[wv][0];

#pragma unroll 1
    for (int part = 0; part < 2; ++part) {
        const int qb = part ? bx : (15 - bx);    // large chunk first
        const int q0w = qb * 128 + wv * 32;
        const int qg = q0w + qc;
        const int ntile = qb * 2 + 2;
        const int ntile_w = qb * 2 + (wv >> 1) + 1;   // per-wave causal clamp

        bf16x8 qf[4];
        {
            const u16* Qp = Q + ((size_t)bh * 2048 + qg) * 64;
#pragma unroll
            for (int c = 0; c < 4; ++c)
                qf[c] = *(const bf16x8*)(Qp + c * 16 + hi * 8);
        }

        f32x16 oacc[2];
#pragma unroll
        for (int r = 0; r < 16; ++r) { oacc[0][r] = 0.0f; oacc[1][r] = 0.0f; }
        float m_run = -60000.0f, l_run = 0.0f;

        stage_kv2(Kb, Vb, 0, Ksm[0], Vsm[0], wv, lane);
        __syncthreads();
        int cur = 0;
        for (int kt = 0; kt < ntile; ++kt) {
            const int key0 = kt * 64;
            if (kt + 1 < ntile)
                stage_kv2(Kb, Vb, key0 + 64, Ksm[cur ^ 1], Vsm[cur ^ 1], wv, lane);
            if (kt < ntile_w) {
                // S^T = K * Q^T
                f32x16 sacc[2];
#pragma unroll
                for (int r = 0; r < 16; ++r) { sacc[0][r] = 0.0f; sacc[1][r] = 0.0f; }
#pragma unroll
                for (int c = 0; c < 4; ++c) {
#pragma unroll
                    for (int kb = 0; kb < 2; ++kb) {
                        const int kr = kb * 32 + qc;
                        const bf16x8 ak = *(const bf16x8*)((const char*)Ksm[cur] + kr * 128 +
                                              ((c * 32 + hi * 16) ^ ((kr & 7) << 4)));
                        sacc[kb] = __builtin_amdgcn_mfma_f32_32x32x16_bf16(ak, qf[c],
                                                                           sacc[kb], 0, 0, 0);
                    }
                }
                float pmax = -1e30f;
                if (key0 + 63 > q0w) {
#pragma unroll
                    for (int kb = 0; kb < 2; ++kb)
#pragma unroll
                        for (int r = 0; r < 16; ++r) {
                            const int key = key0 + kb * 32 + (r & 3) + 8 * (r >> 2) + 4 * hi;
                            float s = sacc[kb][r];
                            if (key > qg) s = -1e30f;
                            sacc[kb][r] = s;
                            pmax = fmaxf(pmax, s);
                        }
                } else {
#pragma unroll
                    for (int kb = 0; kb < 2; ++kb)
#pragma unroll
                        for (int r = 0; r < 16; ++r) pmax = fmaxf(pmax, sacc[kb][r]);
                }
                pmax = fmaxf(pmax, __shfl_xor(pmax, 32));
                if (pmax > m_run + 11.0f) {          // defer-max
                    const float alpha = __builtin_amdgcn_exp2f(m_run - pmax);
#pragma unroll
                    for (int r = 0; r < 16; ++r) { oacc[0][r] *= alpha; oacc[1][r] *= alpha; }
                    l_run *= alpha;
                    m_run = pmax;
                }
                float lsum = 0.0f;
#pragma unroll
                for (int kb = 0; kb < 2; ++kb)
#pragma unroll
                    for (int j = 0; j < 4; ++j) {
                        u16x4 pk4;
#pragma unroll
                        for (int t = 0; t < 4; ++t) {
                            const float e = __builtin_amdgcn_exp2f(sacc[kb][j * 4 + t] - m_run);
                            lsum += e;
                            pk4[t] = f2bf(e);
                        }
                        *(u16x4*)(Pw + qc * 68 + kb * 32 + j * 8 + 4 * hi) = pk4;
                    }
                lsum += __shfl_xor(lsum, 32);
                l_run += lsum;
                // O^T += V^T * P  (P read as two 8B bf16x4 loads: 2-way banks)
#pragma unroll
                for (int c = 0; c < 4; ++c) {
                    const u16* pp = Pw + qc * 68 + c * 16 + hi * 8;
                    union { bf16x8 v; struct { bf16x4 lo; bf16x4 hi2; } s; } u;
                    u.s.lo  = *(const bf16x4*)(pp);
                    u.s.hi2 = *(const bf16x4*)(pp + 4);
                    const bf16x8 pf = u.v;
#pragma unroll
                    for (int db = 0; db < 2; ++db) {
                        const int dr = db * 32 + qc;
                        const bf16x8 av = *(const bf16x8*)((const char*)Vsm[cur] + dr * 128 +
                                              ((c * 32 + hi * 16) ^ ((dr & 7) << 4)));
                        oacc[db] = __builtin_amdgcn_mfma_f32_32x32x16_bf16(av, pf,
                                                                           oacc[db], 0, 0, 0);
                    }
                }
            }
            __syncthreads();
            cur ^= 1;
        }
        const float inv = 1.0f / l_run;
        u16* Yp = &Y[((size_t)(b_ * 2048 + qg)) * 1024 + hh * 64];
#pragma unroll
        for (int db = 0; db < 2; ++db)
#pragma unroll
            for (int j = 0; j < 4; ++j) {
                u16x4 o;
#pragma unroll
                for (int t = 0; t < 4; ++t) o[t] = f2bf(oacc[db][j * 4 + t] * inv);
                *(u16x4*)(Yp + db * 32 + j * 8 + 4 * hi) = o;
            }
    }
}

// ---------------- host ----------------
extern "C" void kernel_launch(void* const* d_in, const int* in_sizes, int n_in,
                              void* d_out, int out_size, void* d_ws, size_t ws_size,
                              hipStream_t stream) {
    (void)in_sizes; (void)n_in; (void)out_size;
    const float* x      = (const float*)d_in[0];
    const float* w_qkv  = (const float*)d_in[2];
    const float* b_qkv  = (const float*)d_in[3];
    const float* w_proj = (const float*)d_in[4];
    const float* b_proj = (const float*)d_in[5];
    const float* w_fc1  = (const float*)d_in[6];
    const float* b_fc1  = (const float*)d_in[7];
    const float* w_fc2  = (const float*)d_in[8];
    const float* b_fc2  = (const float*)d_in[9];
    const float* g1     = (const float*)d_in[10];
    const float* be1    = (const float*)d_in[11];
    const float* g2     = (const float*)d_in[12];
    const float* be2    = (const float*)d_in[13];

    char* ws = (char*)d_ws;
    size_t off = 0;
    auto alloc = [&](size_t bytes) { size_t r = off; off += (bytes + 255) & ~(size_t)255; return r; };
    u16*   wt_qkv = (u16*)(ws + alloc((size_t)3072 * 1024 * 2));
    u16*   wt_prj = (u16*)(ws + alloc((size_t)1024 * 1024 * 2));
    u16*   wt_fc1 = (u16*)(ws + alloc((size_t)4096 * 1024 * 2));
    u16*   wt_fc2 = (u16*)(ws + alloc((size_t)1024 * 4096 * 2));
    u16*   hbuf   = (u16*)(ws + alloc((size_t)4096 * 1024 * 2));
    float* x1     = (float*)(ws + alloc((size_t)4096 * 1024 * 4));
    char*  big    = ws + alloc((size_t)33554432);
    u16* qb  = (u16*)(big);
    u16* kb  = (u16*)(big + 8388608);
    u16* vtb = (u16*)(big + 16777216);
    u16* yb  = (u16*)(big + 25165824);
    u16* act = (u16*)(big);
    if (off > ws_size) return;
    const size_t part_need = (size_t)4 * 4096 * 1024 * 4;   // splitK partials (proj sK2, FC2 sK4)
    if ((ws_size - off) < part_need) return;
    float* part = (float*)(ws + off);

    const dim3 blk(256);
    tcvt_kernel<<<dim3(32, 96), blk, 0, stream>>>(w_qkv, wt_qkv, 1024, 3072);
    tcvt_kernel<<<dim3(32, 32), blk, 0, stream>>>(w_proj, wt_prj, 1024, 1024);
    tcvt_kernel<<<dim3(32, 128), blk, 0, stream>>>(w_fc1, wt_fc1, 1024, 4096);
    tcvt_kernel<<<dim3(128, 32), blk, 0, stream>>>(w_fc2, wt_fc2, 4096, 1024);

    ln_kernel<<<dim3(4096), blk, 0, stream>>>(x, g1, be1, hbuf);
    // QKV: grid 32*24 = 768
    gemmv6<0, 1><<<dim3(768), blk, 0, stream>>>(hbuf, wt_qkv, b_qkv,
                                                qb, kb, vtb, 4096, 3072, 1024);
    // attention: paired triangle, 1D grid, bh-grouped XCD mapping
    attn32_kernel<<<dim3(256), blk, 0, stream>>>(qb, kb, vtb, yb);
    // proj split-K=2: grid 512, then fused reduce(+bias+x residual)+LN2 -> x1, hbuf
    gemmv6<4, 2><<<dim3(512), blk, 0, stream>>>(yb, wt_prj, nullptr,
                                                part, nullptr, nullptr, 4096, 1024, 1024);
    reduceLN_kernel<2><<<dim3(4096), blk, 0, stream>>>(part, b_proj, x, g2, be2,
                                                       x1, hbuf, 1048576);
    // FC1 + GELU: grid 1024
    gemmv6<2, 1><<<dim3(1024), blk, 0, stream>>>(hbuf, wt_fc1, b_fc1,
                                                 act, nullptr, nullptr, 4096, 4096, 1024);
    // FC2 split-K=4: grid 1024, then reduce(+bias+x1) -> d_out
    gemmv6<4, 4><<<dim3(1024), blk, 0, stream>>>(act, wt_fc2, nullptr,
                                                 part, nullptr, nullptr, 4096, 1024, 4096);
    reduceN_kernel<4><<<dim3(4096), blk, 0, stream>>>(part, b_fc2, x1, (float*)d_out,
                                                      1048576, 256);
}

// Round 14
// 239.465 us; speedup vs baseline: 1.0901x; 1.0052x over previous
//
#include <hip/hip_runtime.h>
#include <hip/hip_bf16.h>
#include <stdint.h>

typedef unsigned short u16;
typedef __attribute__((ext_vector_type(8))) short bf16x8;
typedef __attribute__((ext_vector_type(4))) short bf16x4;
typedef __attribute__((ext_vector_type(4))) float f32x4;
typedef __attribute__((ext_vector_type(16))) float f32x16;
typedef __attribute__((ext_vector_type(4))) unsigned short u16x4;

#define DEVI static __device__ __forceinline__

DEVI u16 f2bf(float f) {
    unsigned int u = __builtin_bit_cast(unsigned int, f);
    return (u16)((u + 0x7fffu + ((u >> 16) & 1u)) >> 16);
}

DEVI float gelu_f(float v) {
    // tanh-form GELU: x * sigmoid(1.5957691(x + 0.044715 x^3)); |err vs exact| <= ~3e-4
    const float z = 1.5957691216f * (v + 0.044715f * v * v * v);
    return v / (1.0f + __expf(-z));
}

DEVI void async_copy16(const void* g, void* l) {
    __builtin_amdgcn_global_load_lds((const __attribute__((address_space(1))) void*)g,
                                     (__attribute__((address_space(3))) void*)l,
                                     16, 0, 0);
}

// ---------------- weight transpose + f32->bf16 convert: src[K][N] -> dst[N][K] ----------------
__global__ __launch_bounds__(256) void tcvt_kernel(const float* __restrict__ src,
                                                   u16* __restrict__ dst,
                                                   int K, int N) {
    __shared__ float tile[32][33];
    const int k0 = blockIdx.x * 32, n0 = blockIdx.y * 32;
    const int t = threadIdx.x;
    const int c = t & 31, r0 = t >> 5;
#pragma unroll
    for (int p = 0; p < 4; ++p) {
        const int r = r0 + p * 8;
        tile[r][c] = src[(size_t)(k0 + r) * N + n0 + c];
    }
    __syncthreads();
#pragma unroll
    for (int p = 0; p < 4; ++p) {
        const int r = r0 + p * 8;
        dst[(size_t)(n0 + r) * K + k0 + c] = f2bf(tile[c][r]);
    }
}

// ---------------- LayerNorm (f32 in) -> bf16 out ----------------
__global__ __launch_bounds__(256) void ln_kernel(const float* __restrict__ x,
                                                 const float* __restrict__ gw,
                                                 const float* __restrict__ bw,
                                                 u16* __restrict__ out) {
    const int row = blockIdx.x;
    const int t = threadIdx.x;
    const float4 v = ((const float4*)(x + (size_t)row * 1024))[t];
    float s  = v.x + v.y + v.z + v.w;
    float ss = v.x * v.x + v.y * v.y + v.z * v.z + v.w * v.w;
#pragma unroll
    for (int off = 32; off > 0; off >>= 1) {
        s  += __shfl_down(s, off);
        ss += __shfl_down(ss, off);
    }
    __shared__ float red[8];
    const int wv = t >> 6;
    if ((t & 63) == 0) { red[wv] = s; red[4 + wv] = ss; }
    __syncthreads();
    if (t == 0) {
        red[0] = red[0] + red[1] + red[2] + red[3];
        red[4] = red[4] + red[5] + red[6] + red[7];
    }
    __syncthreads();
    const float mean = red[0] * (1.0f / 1024.0f);
    const float var  = red[4] * (1.0f / 1024.0f) - mean * mean;
    const float rstd = rsqrtf(var + 1e-5f);
    const float4 gv = ((const float4*)gw)[t];
    const float4 bv = ((const float4*)bw)[t];
    u16x4 o;
    o[0] = f2bf((v.x - mean) * rstd * gv.x + bv.x);
    o[1] = f2bf((v.y - mean) * rstd * gv.y + bv.y);
    o[2] = f2bf((v.z - mean) * rstd * gv.z + bv.z);
    o[3] = f2bf((v.w - mean) * rstd * gv.w + bv.w);
    ((u16x4*)out)[(size_t)row * 256 + t] = o;
}

// ================= 128x128 GEMM, BK=64, single-buffer, m97-pure schedule =================
DEVI void stage64(const char* g, size_t ldb, char* lds0, int lane, int wv) {
    const int colsw = ((lane & 3) << 4) ^ (lane & 32);  // inverse-swizzled source col bytes
    const int rl = lane >> 2;
#pragma unroll
    for (int i = 0; i < 4; ++i) {
        const int s = wv * 4 + i;            // slot 0..15
        const int kh = s >> 3, c = s & 7;    // k-half, 16-row subtile
        async_copy16(g + (size_t)(c * 16 + rl) * ldb + kh * 64 + colsw,
                     lds0 + s * 1024);
    }
}

// EPI 0: QKV scatter. EPI 2: gelu->bf16. EPI 4: f32 partial (split-K).
template <int EPI, int SPLITK>
__global__ __launch_bounds__(256, 4) void gemmv6(const u16* __restrict__ A,
                                                 const u16* __restrict__ Bt,
                                                 const float* __restrict__ bias,
                                                 void* __restrict__ out0,
                                                 void* __restrict__ out1,
                                                 void* __restrict__ out2,
                                                 int M, int N, int K) {
    __shared__ __align__(16) char As[16384];
    __shared__ __align__(16) char Bs[16384];
    const int tid = threadIdx.x;
    const int lane = tid & 63, wv = tid >> 6;
    const int wr = wv >> 1, wc = wv & 1;        // 2M x 2N waves, 64x64 each
    const int g = lane >> 4, qq = lane & 15;
    const int rdoff = qq * 64 + ((g * 16) ^ ((qq & 8) << 2));  // swizzled read offset

    const int nwg = gridDim.x;
    int id = blockIdx.x;
    id = (id & 7) * (nwg >> 3) + (id >> 3);
    const int MT = M >> 7, NTn = N >> 7;
    const int slice = id / (MT * NTn);
    const int r2 = id % (MT * NTn);
    const int m0 = (r2 % MT) << 7;
    const int n0 = (r2 / MT) << 7;
    const int Ks = K / SPLITK;
    const int NT = Ks >> 6;
    const size_t ldb = (size_t)K * 2;

    const char* pa = (const char*)A + (size_t)m0 * ldb + (size_t)slice * Ks * 2;
    const char* pb = (const char*)Bt + (size_t)n0 * ldb + (size_t)slice * Ks * 2;

    f32x4 acc[4][4] = {};

    for (int t = 0; t < NT; ++t) {
        stage64(pa + (size_t)t * 128, ldb, As, lane, wv);
        stage64(pb + (size_t)t * 128, ldb, Bs, lane, wv);
        __syncthreads();
#pragma unroll
        for (int kh = 0; kh < 2; ++kh) {
            bf16x8 fa[4], fb[4];
#pragma unroll
            for (int fn = 0; fn < 4; ++fn)
                fb[fn] = *(const bf16x8*)(Bs + (kh * 8 + wc * 4 + fn) * 1024 + rdoff);
#pragma unroll
            for (int fm = 0; fm < 4; ++fm)
                fa[fm] = *(const bf16x8*)(As + (kh * 8 + wr * 4 + fm) * 1024 + rdoff);
#pragma unroll
            for (int fm = 0; fm < 4; ++fm)
#pragma unroll
                for (int fn = 0; fn < 4; ++fn)
                    acc[fm][fn] = __builtin_amdgcn_mfma_f32_16x16x32_bf16(fa[fm], fb[fn],
                                                                          acc[fm][fn], 0, 0, 0);
        }
        __syncthreads();
    }

#pragma unroll
    for (int fm = 0; fm < 4; ++fm) {
#pragma unroll
        for (int fn = 0; fn < 4; ++fn) {
            const int mrow = m0 + wr * 64 + fm * 16 + g * 4;
            const int ncol = n0 + wc * 64 + fn * 16 + qq;
            if constexpr (EPI == 0) {
                const float bs = bias[ncol];
                const int sec = ncol >> 10;
                const int hd_ = ncol & 1023;
                const int hh = hd_ >> 6, dd = hd_ & 63;
                if (sec == 2) {
                    const int b_ = mrow >> 11, l_ = mrow & 2047;
                    u16x4 pk;
#pragma unroll
                    for (int r = 0; r < 4; ++r) pk[r] = f2bf(acc[fm][fn][r] + bs);
                    *(u16x4*)((u16*)out2 + ((size_t)((b_ * 16 + hh) * 64 + dd)) * 2048 + l_) = pk;
                } else {
                    u16* dst = (sec == 0) ? (u16*)out0 : (u16*)out1;
                    // q-scale folds softmax 1/sqrt(hd) AND log2(e) for exp2-domain softmax
                    const float sc = (sec == 0) ? 0.1803368801f : 1.0f;
#pragma unroll
                    for (int r = 0; r < 4; ++r) {
                        const int mr = mrow + r;
                        const int b_ = mr >> 11, l_ = mr & 2047;
                        dst[((size_t)((b_ * 16 + hh) * 2048 + l_)) * 64 + dd] =
                            f2bf((acc[fm][fn][r] + bs) * sc);
                    }
                }
            } else if constexpr (EPI == 2) {
                const float bs = bias[ncol];
                u16* dst = (u16*)out0;
#pragma unroll
                for (int r = 0; r < 4; ++r)
                    dst[(size_t)(mrow + r) * N + ncol] = f2bf(gelu_f(acc[fm][fn][r] + bs));
            } else {  // EPI 4: raw f32 partial for split-K
                float* dst = (float*)out0 + (size_t)slice * M * N;
#pragma unroll
                for (int r = 0; r < 4; ++r)
                    dst[(size_t)(mrow + r) * N + ncol] = acc[fm][fn][r];
            }
        }
    }
}

// split-K reduce + bias + residual -> f32 out (final FC2 path)
template <int SPLIT>
__global__ __launch_bounds__(256) void reduceN_kernel(const float* __restrict__ p,
                                                      const float* __restrict__ bias,
                                                      const float* __restrict__ res,
                                                      float* __restrict__ out,
                                                      int MN4, int N4) {
    const int i = blockIdx.x * 256 + threadIdx.x;   // one float4
    float4 s = ((const float4*)p)[i];
#pragma unroll
    for (int s2 = 1; s2 < SPLIT; ++s2) {
        const float4 q = ((const float4*)p)[(size_t)s2 * MN4 + i];
        s.x += q.x; s.y += q.y; s.z += q.z; s.w += q.w;
    }
    const float4 r = ((const float4*)res)[i];
    const float4 bs = ((const float4*)bias)[i & (N4 - 1)];
    float4 o;
    o.x = s.x + r.x + bs.x;
    o.y = s.y + r.y + bs.y;
    o.z = s.z + r.z + bs.z;
    o.w = s.w + r.w + bs.w;
    ((float4*)out)[i] = o;
}

// split-K reduce + bias + residual + LayerNorm fused (proj path):
// one block per row (1024 floats = 256 float4). Writes x1 (f32) AND ln(x1) (bf16).
template <int SPLIT>
__global__ __launch_bounds__(256) void reduceLN_kernel(const float* __restrict__ p,
                                                       const float* __restrict__ bias,
                                                       const float* __restrict__ res,
                                                       const float* __restrict__ gw,
                                                       const float* __restrict__ bw,
                                                       float* __restrict__ xout,
                                                       u16* __restrict__ lnout,
                                                       int MN4) {
    const int row = blockIdx.x;
    const int t = threadIdx.x;
    const int i = row * 256 + t;
    float4 s = ((const float4*)p)[i];
#pragma unroll
    for (int s2 = 1; s2 < SPLIT; ++s2) {
        const float4 q = ((const float4*)p)[(size_t)s2 * MN4 + i];
        s.x += q.x; s.y += q.y; s.z += q.z; s.w += q.w;
    }
    const float4 r = ((const float4*)res)[i];
    const float4 bs = ((const float4*)bias)[t];
    float4 o;
    o.x = s.x + r.x + bs.x;
    o.y = s.y + r.y + bs.y;
    o.z = s.z + r.z + bs.z;
    o.w = s.w + r.w + bs.w;
    ((float4*)xout)[i] = o;
    // LayerNorm over the row
    float sum  = o.x + o.y + o.z + o.w;
    float ssum = o.x * o.x + o.y * o.y + o.z * o.z + o.w * o.w;
#pragma unroll
    for (int off = 32; off > 0; off >>= 1) {
        sum  += __shfl_down(sum, off);
        ssum += __shfl_down(ssum, off);
    }
    __shared__ float red[8];
    const int wv = t >> 6;
    if ((t & 63) == 0) { red[wv] = sum; red[4 + wv] = ssum; }
    __syncthreads();
    if (t == 0) {
        red[0] = red[0] + red[1] + red[2] + red[3];
        red[4] = red[4] + red[5] + red[6] + red[7];
    }
    __syncthreads();
    const float mean = red[0] * (1.0f / 1024.0f);
    const float var  = red[4] * (1.0f / 1024.0f) - mean * mean;
    const float rstd = rsqrtf(var + 1e-5f);
    const float4 gv = ((const float4*)gw)[t];
    const float4 bv = ((const float4*)bw)[t];
    u16x4 ov;
    ov[0] = f2bf((o.x - mean) * rstd * gv.x + bv.x);
    ov[1] = f2bf((o.y - mean) * rstd * gv.y + bv.y);
    ov[2] = f2bf((o.z - mean) * rstd * gv.z + bv.z);
    ov[3] = f2bf((o.w - mean) * rstd * gv.w + bv.w);
    ((u16x4*)lnout)[(size_t)row * 256 + t] = ov;
}

// ---------------- causal flash attention (unpaired, XCD-grouped, 2 blocks/CU) ----------
// Grid = 512 blocks 1D: bh = id & 31, qb = 15 - (id >> 5). XCD = id % 8 = bh % 8, so all
// 16 blocks sharing one bh's K/V land on ONE XCD (L2-resident, verified R13: FETCH 74->12 MB).
// UNPAIRED chunks -> 512 blocks = 2 blocks/CU: each SIMD carries 2 waves whose serial
// QK->softmax->PV chains interleave (R13 showed 1 wave/SIMD leaves SIMD ~65% idle).
// Longest chains (qb=15) dispatch first; short blocks backfill.
// Swapped S^T = K*Q^T; exp2-domain softmax; defer-max THR=11; P stride 68 u16.
DEVI void stage_kv2(const char* kbase, const char* vbase, int key0,
                    u16* ksm, u16* vsm, int wv, int lane) {
#pragma unroll
    for (int i = 0; i < 2; ++i) {
        const int c = wv + i * 4;
        const int off = c * 1024 + lane * 16;
        const int row = off >> 7;
        const int scol = (off & 127) ^ ((row & 7) << 4);
        async_copy16(kbase + (size_t)key0 * 128 + (size_t)row * 128 + scol,
                     (char*)ksm + c * 1024);
    }
#pragma unroll
    for (int i = 0; i < 2; ++i) {
        const int c = wv + i * 4;
        const int row = c * 8 + (lane >> 3);
        const int scol = ((lane & 7) * 16) ^ ((row & 7) << 4);
        async_copy16(vbase + (size_t)row * 4096 + (size_t)key0 * 2 + scol,
                     (char*)vsm + c * 1024);
    }
}

__global__ __launch_bounds__(256, 3) void attn32_kernel(const u16* __restrict__ Q,
                                                        const u16* __restrict__ Kk,
                                                        const u16* __restrict__ Vt,
                                                        u16* __restrict__ Y) {
    const int id = blockIdx.x;
    const int bh = id & 31;                    // XCD = id % 8 = bh % 8 -> K/V L2-resident
    const int qb = 15 - (id >> 5);             // longest chains dispatch first
    const int b_ = bh >> 4, hh = bh & 15;
    const int tid = threadIdx.x;
    const int wv = tid >> 6, lane = tid & 63;
    const int hi = lane >> 5, qc = lane & 31;

    __shared__ __align__(16) u16 Ksm[2][4096];
    __shared__ __align__(16) u16 Vsm[2][4096];
    __shared__ __align__(16) u16 Pl[4][32 * 68];   // per-wave P[q][key], stride 68 u16

    const char* Kb = (const char*)(Kk + (size_t)bh * 2048 * 64);
    const char* Vb = (const char*)(Vt + (size_t)bh * 64 * 2048);
    u16* Pw = &Pl[wv][0];

    const int q0w = qb * 128 + wv * 32;
    const int qg = q0w + qc;
    const int ntile = qb * 2 + 2;
    const int ntile_w = qb * 2 + (wv >> 1) + 1;   // per-wave causal clamp

    bf16x8 qf[4];
    {
        const u16* Qp = Q + ((size_t)bh * 2048 + qg) * 64;
#pragma unroll
        for (int c = 0; c < 4; ++c)
            qf[c] = *(const bf16x8*)(Qp + c * 16 + hi * 8);
    }

    f32x16 oacc[2];
#pragma unroll
    for (int r = 0; r < 16; ++r) { oacc[0][r] = 0.0f; oacc[1][r] = 0.0f; }
    float m_run = -60000.0f, l_run = 0.0f;

    stage_kv2(Kb, Vb, 0, Ksm[0], Vsm[0], wv, lane);
    __syncthreads();
    int cur = 0;
    for (int kt = 0; kt < ntile; ++kt) {
        const int key0 = kt * 64;
        if (kt + 1 < ntile)
            stage_kv2(Kb, Vb, key0 + 64, Ksm[cur ^ 1], Vsm[cur ^ 1], wv, lane);
        if (kt < ntile_w) {
            // S^T = K * Q^T
            f32x16 sacc[2];
#pragma unroll
            for (int r = 0; r < 16; ++r) { sacc[0][r] = 0.0f; sacc[1][r] = 0.0f; }
#pragma unroll
            for (int c = 0; c < 4; ++c) {
#pragma unroll
                for (int kb = 0; kb < 2; ++kb) {
                    const int kr = kb * 32 + qc;
                    const bf16x8 ak = *(const bf16x8*)((const char*)Ksm[cur] + kr * 128 +
                                          ((c * 32 + hi * 16) ^ ((kr & 7) << 4)));
                    sacc[kb] = __builtin_amdgcn_mfma_f32_32x32x16_bf16(ak, qf[c],
                                                                       sacc[kb], 0, 0, 0);
                }
            }
            float pmax = -1e30f;
            if (key0 + 63 > q0w) {
#pragma unroll
                for (int kb = 0; kb < 2; ++kb)
#pragma unroll
                    for (int r = 0; r < 16; ++r) {
                        const int key = key0 + kb * 32 + (r & 3) + 8 * (r >> 2) + 4 * hi;
                        float s = sacc[kb][r];
                        if (key > qg) s = -1e30f;
                        sacc[kb][r] = s;
                        pmax = fmaxf(pmax, s);
                    }
            } else {
#pragma unroll
                for (int kb = 0; kb < 2; ++kb)
#pragma unroll
                    for (int r = 0; r < 16; ++r) pmax = fmaxf(pmax, sacc[kb][r]);
            }
            pmax = fmaxf(pmax, __shfl_xor(pmax, 32));
            if (pmax > m_run + 11.0f) {          // defer-max
                const float alpha = __builtin_amdgcn_exp2f(m_run - pmax);
#pragma unroll
                for (int r = 0; r < 16; ++r) { oacc[0][r] *= alpha; oacc[1][r] *= alpha; }
                l_run *= alpha;
                m_run = pmax;
            }
            float lsum = 0.0f;
#pragma unroll
            for (int kb = 0; kb < 2; ++kb)
#pragma unroll
                for (int j = 0; j < 4; ++j) {
                    u16x4 pk4;
#pragma unroll
                    for (int t = 0; t < 4; ++t) {
                        const float e = __builtin_amdgcn_exp2f(sacc[kb][j * 4 + t] - m_run);
                        lsum += e;
                        pk4[t] = f2bf(e);
                    }
                    *(u16x4*)(Pw + qc * 68 + kb * 32 + j * 8 + 4 * hi) = pk4;
                }
            lsum += __shfl_xor(lsum, 32);
            l_run += lsum;
            // O^T += V^T * P  (P read as two 8B bf16x4 loads: 2-way banks)
#pragma unroll
            for (int c = 0; c < 4; ++c) {
                const u16* pp = Pw + qc * 68 + c * 16 + hi * 8;
                union { bf16x8 v; struct { bf16x4 lo; bf16x4 hi2; } s; } u;
                u.s.lo  = *(const bf16x4*)(pp);
                u.s.hi2 = *(const bf16x4*)(pp + 4);
                const bf16x8 pf = u.v;
#pragma unroll
                for (int db = 0; db < 2; ++db) {
                    const int dr = db * 32 + qc;
                    const bf16x8 av = *(const bf16x8*)((const char*)Vsm[cur] + dr * 128 +
                                          ((c * 32 + hi * 16) ^ ((dr & 7) << 4)));
                    oacc[db] = __builtin_amdgcn_mfma_f32_32x32x16_bf16(av, pf,
                                                                       oacc[db], 0, 0, 0);
                }
            }
        }
        __syncthreads();
        cur ^= 1;
    }
    const float inv = 1.0f / l_run;
    u16* Yp = &Y[((size_t)(b_ * 2048 + qg)) * 1024 + hh * 64];
#pragma unroll
    for (int db = 0; db < 2; ++db)
#pragma unroll
        for (int j = 0; j < 4; ++j) {
            u16x4 o;
#pragma unroll
            for (int t = 0; t < 4; ++t) o[t] = f2bf(oacc[db][j * 4 + t] * inv);
            *(u16x4*)(Yp + db * 32 + j * 8 + 4 * hi) = o;
        }
}

// ---------------- host ----------------
extern "C" void kernel_launch(void* const* d_in, const int* in_sizes, int n_in,
                              void* d_out, int out_size, void* d_ws, size_t ws_size,
                              hipStream_t stream) {
    (void)in_sizes; (void)n_in; (void)out_size;
    const float* x      = (const float*)d_in[0];
    const float* w_qkv  = (const float*)d_in[2];
    const float* b_qkv  = (const float*)d_in[3];
    const float* w_proj = (const float*)d_in[4];
    const float* b_proj = (const float*)d_in[5];
    const float* w_fc1  = (const float*)d_in[6];
    const float* b_fc1  = (const float*)d_in[7];
    const float* w_fc2  = (const float*)d_in[8];
    const float* b_fc2  = (const float*)d_in[9];
    const float* g1     = (const float*)d_in[10];
    const float* be1    = (const float*)d_in[11];
    const float* g2     = (const float*)d_in[12];
    const float* be2    = (const float*)d_in[13];

    char* ws = (char*)d_ws;
    size_t off = 0;
    auto alloc = [&](size_t bytes) { size_t r = off; off += (bytes + 255) & ~(size_t)255; return r; };
    u16*   wt_qkv = (u16*)(ws + alloc((size_t)3072 * 1024 * 2));
    u16*   wt_prj = (u16*)(ws + alloc((size_t)1024 * 1024 * 2));
    u16*   wt_fc1 = (u16*)(ws + alloc((size_t)4096 * 1024 * 2));
    u16*   wt_fc2 = (u16*)(ws + alloc((size_t)1024 * 4096 * 2));
    u16*   hbuf   = (u16*)(ws + alloc((size_t)4096 * 1024 * 2));
    float* x1     = (float*)(ws + alloc((size_t)4096 * 1024 * 4));
    char*  big    = ws + alloc((size_t)33554432);
    u16* qb  = (u16*)(big);
    u16* kb  = (u16*)(big + 8388608);
    u16* vtb = (u16*)(big + 16777216);
    u16* yb  = (u16*)(big + 25165824);
    u16* act = (u16*)(big);
    if (off > ws_size) return;
    const size_t part_need = (size_t)4 * 4096 * 1024 * 4;   // splitK partials (proj sK2, FC2 sK4)
    if ((ws_size - off) < part_need) return;
    float* part = (float*)(ws + off);

    const dim3 blk(256);
    tcvt_kernel<<<dim3(32, 96), blk, 0, stream>>>(w_qkv, wt_qkv, 1024, 3072);
    tcvt_kernel<<<dim3(32, 32), blk, 0, stream>>>(w_proj, wt_prj, 1024, 1024);
    tcvt_kernel<<<dim3(32, 128), blk, 0, stream>>>(w_fc1, wt_fc1, 1024, 4096);
    tcvt_kernel<<<dim3(128, 32), blk, 0, stream>>>(w_fc2, wt_fc2, 4096, 1024);

    ln_kernel<<<dim3(4096), blk, 0, stream>>>(x, g1, be1, hbuf);
    // QKV: grid 32*24 = 768
    gemmv6<0, 1><<<dim3(768), blk, 0, stream>>>(hbuf, wt_qkv, b_qkv,
                                                qb, kb, vtb, 4096, 3072, 1024);
    // attention: unpaired 16 chunks x 32 bh = 512 blocks (2/CU), XCD-grouped, longest first
    attn32_kernel<<<dim3(512), blk, 0, stream>>>(qb, kb, vtb, yb);
    // proj split-K=2: grid 512, then fused reduce(+bias+x residual)+LN2 -> x1, hbuf
    gemmv6<4, 2><<<dim3(512), blk, 0, stream>>>(yb, wt_prj, nullptr,
                                                part, nullptr, nullptr, 4096, 1024, 1024);
    reduceLN_kernel<2><<<dim3(4096), blk, 0, stream>>>(part, b_proj, x, g2, be2,
                                                       x1, hbuf, 1048576);
    // FC1 + GELU: grid 1024
    gemmv6<2, 1><<<dim3(1024), blk, 0, stream>>>(hbuf, wt_fc1, b_fc1,
                                                 act, nullptr, nullptr, 4096, 4096, 1024);
    // FC2 split-K=4: grid 1024, then reduce(+bias+x1) -> d_out
    gemmv6<4, 4><<<dim3(1024), blk, 0, stream>>>(act, wt_fc2, nullptr,
                                                 part, nullptr, nullptr, 4096, 1024, 4096);
    reduceN_kernel<4><<<dim3(4096), blk, 0, stream>>>(part, b_fc2, x1, (float*)d_out,
                                                      1048576, 256);
}

// Round 15
// 220.923 us; speedup vs baseline: 1.1816x; 1.0839x over previous
//
#include <hip/hip_runtime.h>
#include <hip/hip_bf16.h>
#include <stdint.h>

typedef unsigned short u16;
typedef __attribute__((ext_vector_type(8))) short bf16x8;
typedef __attribute__((ext_vector_type(4))) short bf16x4;
typedef __attribute__((ext_vector_type(4))) float f32x4;
typedef __attribute__((ext_vector_type(16))) float f32x16;
typedef __attribute__((ext_vector_type(4))) unsigned short u16x4;

#define DEVI static __device__ __forceinline__

DEVI u16 f2bf(float f) {
    unsigned int u = __builtin_bit_cast(unsigned int, f);
    return (u16)((u + 0x7fffu + ((u >> 16) & 1u)) >> 16);
}

DEVI float bf2f(u16 v) { return __builtin_bit_cast(float, ((unsigned)v) << 16); }

DEVI float4 ldbf4(const u16* p, size_t idx4) {
    const u16x4 v = ((const u16x4*)p)[idx4];
    float4 o;
    o.x = bf2f(v[0]); o.y = bf2f(v[1]); o.z = bf2f(v[2]); o.w = bf2f(v[3]);
    return o;
}

DEVI float gelu_f(float v) {
    // tanh-form GELU: x * sigmoid(1.5957691(x + 0.044715 x^3)); |err vs exact| <= ~3e-4
    const float z = 1.5957691216f * (v + 0.044715f * v * v * v);
    return v / (1.0f + __expf(-z));
}

DEVI void async_copy16(const void* g, void* l) {
    __builtin_amdgcn_global_load_lds((const __attribute__((address_space(1))) void*)g,
                                     (__attribute__((address_space(3))) void*)l,
                                     16, 0, 0);
}

// ============ prep kernel: 4x weight transpose-convert + LN1, one launch ============
// blocks [0,3072) qkv, [3072,4096) proj, [4096,8192) fc1, [8192,12288) fc2,
// [12288,16384) LN1 rows. Whole-block branches (uniform).
__global__ __launch_bounds__(256) void prep_kernel(const float* __restrict__ wq, u16* __restrict__ dq,
                                                   const float* __restrict__ wp, u16* __restrict__ dp,
                                                   const float* __restrict__ w1, u16* __restrict__ d1,
                                                   const float* __restrict__ w2, u16* __restrict__ d2,
                                                   const float* __restrict__ x,
                                                   const float* __restrict__ g1,
                                                   const float* __restrict__ be1,
                                                   u16* __restrict__ ln1out) {
    __shared__ float tile[32][33];
    __shared__ float red[8];
    const int id = blockIdx.x;
    const int t = threadIdx.x;
    if (id >= 12288) {
        // ---- LN1 row ----
        const int row = id - 12288;
        const float4 v = ((const float4*)(x + (size_t)row * 1024))[t];
        float s  = v.x + v.y + v.z + v.w;
        float ss = v.x * v.x + v.y * v.y + v.z * v.z + v.w * v.w;
#pragma unroll
        for (int off = 32; off > 0; off >>= 1) {
            s  += __shfl_down(s, off);
            ss += __shfl_down(ss, off);
        }
        const int wv = t >> 6;
        if ((t & 63) == 0) { red[wv] = s; red[4 + wv] = ss; }
        __syncthreads();
        if (t == 0) {
            red[0] = red[0] + red[1] + red[2] + red[3];
            red[4] = red[4] + red[5] + red[6] + red[7];
        }
        __syncthreads();
        const float mean = red[0] * (1.0f / 1024.0f);
        const float var  = red[4] * (1.0f / 1024.0f) - mean * mean;
        const float rstd = rsqrtf(var + 1e-5f);
        const float4 gv = ((const float4*)g1)[t];
        const float4 bv = ((const float4*)be1)[t];
        u16x4 o;
        o[0] = f2bf((v.x - mean) * rstd * gv.x + bv.x);
        o[1] = f2bf((v.y - mean) * rstd * gv.y + bv.y);
        o[2] = f2bf((v.z - mean) * rstd * gv.z + bv.z);
        o[3] = f2bf((v.w - mean) * rstd * gv.w + bv.w);
        ((u16x4*)ln1out)[(size_t)row * 256 + t] = o;
        return;
    }
    // ---- transpose-convert tile ----
    const float* src; u16* dst; int K, N, k0, n0;
    if (id < 3072)      {               src = wq; dst = dq; K = 1024; N = 3072; k0 = (id & 31) << 5; n0 = (id >> 5) << 5; }
    else if (id < 4096) { int l = id - 3072; src = wp; dst = dp; K = 1024; N = 1024; k0 = (l & 31) << 5; n0 = (l >> 5) << 5; }
    else if (id < 8192) { int l = id - 4096; src = w1; dst = d1; K = 1024; N = 4096; k0 = (l & 31) << 5; n0 = (l >> 5) << 5; }
    else                { int l = id - 8192; src = w2; dst = d2; K = 4096; N = 1024; k0 = (l & 127) << 5; n0 = (l >> 7) << 5; }
    const int c = t & 31, r0 = t >> 5;
#pragma unroll
    for (int p = 0; p < 4; ++p) {
        const int r = r0 + p * 8;
        tile[r][c] = src[(size_t)(k0 + r) * N + n0 + c];
    }
    __syncthreads();
#pragma unroll
    for (int p = 0; p < 4; ++p) {
        const int r = r0 + p * 8;
        dst[(size_t)(n0 + r) * K + k0 + c] = f2bf(tile[c][r]);
    }
}

// ================= 128x128 GEMM, BK=64, single-buffer, m97-pure schedule =================
DEVI void stage64(const char* g, size_t ldb, char* lds0, int lane, int wv) {
    const int colsw = ((lane & 3) << 4) ^ (lane & 32);  // inverse-swizzled source col bytes
    const int rl = lane >> 2;
#pragma unroll
    for (int i = 0; i < 4; ++i) {
        const int s = wv * 4 + i;            // slot 0..15
        const int kh = s >> 3, c = s & 7;    // k-half, 16-row subtile
        async_copy16(g + (size_t)(c * 16 + rl) * ldb + kh * 64 + colsw,
                     lds0 + s * 1024);
    }
}

// EPI 0: QKV scatter. EPI 2: gelu->bf16. EPI 5: bf16 partial (split-K).
template <int EPI, int SPLITK>
__global__ __launch_bounds__(256, 4) void gemmv6(const u16* __restrict__ A,
                                                 const u16* __restrict__ Bt,
                                                 const float* __restrict__ bias,
                                                 void* __restrict__ out0,
                                                 void* __restrict__ out1,
                                                 void* __restrict__ out2,
                                                 int M, int N, int K) {
    __shared__ __align__(16) char As[16384];
    __shared__ __align__(16) char Bs[16384];
    const int tid = threadIdx.x;
    const int lane = tid & 63, wv = tid >> 6;
    const int wr = wv >> 1, wc = wv & 1;        // 2M x 2N waves, 64x64 each
    const int g = lane >> 4, qq = lane & 15;
    const int rdoff = qq * 64 + ((g * 16) ^ ((qq & 8) << 2));  // swizzled read offset

    const int nwg = gridDim.x;
    int id = blockIdx.x;
    id = (id & 7) * (nwg >> 3) + (id >> 3);
    const int MT = M >> 7, NTn = N >> 7;
    const int slice = id / (MT * NTn);
    const int r2 = id % (MT * NTn);
    const int m0 = (r2 % MT) << 7;
    const int n0 = (r2 / MT) << 7;
    const int Ks = K / SPLITK;
    const int NT = Ks >> 6;
    const size_t ldb = (size_t)K * 2;

    const char* pa = (const char*)A + (size_t)m0 * ldb + (size_t)slice * Ks * 2;
    const char* pb = (const char*)Bt + (size_t)n0 * ldb + (size_t)slice * Ks * 2;

    f32x4 acc[4][4] = {};

    for (int t = 0; t < NT; ++t) {
        stage64(pa + (size_t)t * 128, ldb, As, lane, wv);
        stage64(pb + (size_t)t * 128, ldb, Bs, lane, wv);
        __syncthreads();
#pragma unroll
        for (int kh = 0; kh < 2; ++kh) {
            bf16x8 fa[4], fb[4];
#pragma unroll
            for (int fn = 0; fn < 4; ++fn)
                fb[fn] = *(const bf16x8*)(Bs + (kh * 8 + wc * 4 + fn) * 1024 + rdoff);
#pragma unroll
            for (int fm = 0; fm < 4; ++fm)
                fa[fm] = *(const bf16x8*)(As + (kh * 8 + wr * 4 + fm) * 1024 + rdoff);
#pragma unroll
            for (int fm = 0; fm < 4; ++fm)
#pragma unroll
                for (int fn = 0; fn < 4; ++fn)
                    acc[fm][fn] = __builtin_amdgcn_mfma_f32_16x16x32_bf16(fa[fm], fb[fn],
                                                                          acc[fm][fn], 0, 0, 0);
        }
        __syncthreads();
    }

#pragma unroll
    for (int fm = 0; fm < 4; ++fm) {
#pragma unroll
        for (int fn = 0; fn < 4; ++fn) {
            const int mrow = m0 + wr * 64 + fm * 16 + g * 4;
            const int ncol = n0 + wc * 64 + fn * 16 + qq;
            if constexpr (EPI == 0) {
                const float bs = bias[ncol];
                const int sec = ncol >> 10;
                const int hd_ = ncol & 1023;
                const int hh = hd_ >> 6, dd = hd_ & 63;
                if (sec == 2) {
                    const int b_ = mrow >> 11, l_ = mrow & 2047;
                    u16x4 pk;
#pragma unroll
                    for (int r = 0; r < 4; ++r) pk[r] = f2bf(acc[fm][fn][r] + bs);
                    *(u16x4*)((u16*)out2 + ((size_t)((b_ * 16 + hh) * 64 + dd)) * 2048 + l_) = pk;
                } else {
                    u16* dst = (sec == 0) ? (u16*)out0 : (u16*)out1;
                    // q-scale folds softmax 1/sqrt(hd) AND log2(e) for exp2-domain softmax
                    const float sc = (sec == 0) ? 0.1803368801f : 1.0f;
#pragma unroll
                    for (int r = 0; r < 4; ++r) {
                        const int mr = mrow + r;
                        const int b_ = mr >> 11, l_ = mr & 2047;
                        dst[((size_t)((b_ * 16 + hh) * 2048 + l_)) * 64 + dd] =
                            f2bf((acc[fm][fn][r] + bs) * sc);
                    }
                }
            } else if constexpr (EPI == 2) {
                const float bs = bias[ncol];
                u16* dst = (u16*)out0;
#pragma unroll
                for (int r = 0; r < 4; ++r)
                    dst[(size_t)(mrow + r) * N + ncol] = f2bf(gelu_f(acc[fm][fn][r] + bs));
            } else {  // EPI 5: bf16 partial for split-K
                u16* dst = (u16*)out0 + (size_t)slice * M * N;
#pragma unroll
                for (int r = 0; r < 4; ++r)
                    dst[(size_t)(mrow + r) * N + ncol] = f2bf(acc[fm][fn][r]);
            }
        }
    }
}

// split-K reduce (bf16 partials) + bias + residual -> f32 out (FC2 path)
template <int SPLIT>
__global__ __launch_bounds__(256) void reduceN_kernel(const u16* __restrict__ p,
                                                      const float* __restrict__ bias,
                                                      const float* __restrict__ res,
                                                      float* __restrict__ out,
                                                      int MN4, int N4) {
    const int i = blockIdx.x * 256 + threadIdx.x;   // one float4
    float4 s = ldbf4(p, i);
#pragma unroll
    for (int s2 = 1; s2 < SPLIT; ++s2) {
        const float4 q = ldbf4(p, (size_t)s2 * MN4 + i);
        s.x += q.x; s.y += q.y; s.z += q.z; s.w += q.w;
    }
    const float4 r = ((const float4*)res)[i];
    const float4 bs = ((const float4*)bias)[i & (N4 - 1)];
    float4 o;
    o.x = s.x + r.x + bs.x;
    o.y = s.y + r.y + bs.y;
    o.z = s.z + r.z + bs.z;
    o.w = s.w + r.w + bs.w;
    ((float4*)out)[i] = o;
}

// split-K reduce (bf16 partials) + bias + residual + LayerNorm fused (proj path):
// one block per row. Writes x1 (f32) AND ln(x1) (bf16).
template <int SPLIT>
__global__ __launch_bounds__(256) void reduceLN_kernel(const u16* __restrict__ p,
                                                       const float* __restrict__ bias,
                                                       const float* __restrict__ res,
                                                       const float* __restrict__ gw,
                                                       const float* __restrict__ bw,
                                                       float* __restrict__ xout,
                                                       u16* __restrict__ lnout,
                                                       int MN4) {
    const int row = blockIdx.x;
    const int t = threadIdx.x;
    const int i = row * 256 + t;
    float4 s = ldbf4(p, i);
#pragma unroll
    for (int s2 = 1; s2 < SPLIT; ++s2) {
        const float4 q = ldbf4(p, (size_t)s2 * MN4 + i);
        s.x += q.x; s.y += q.y; s.z += q.z; s.w += q.w;
    }
    const float4 r = ((const float4*)res)[i];
    const float4 bs = ((const float4*)bias)[t];
    float4 o;
    o.x = s.x + r.x + bs.x;
    o.y = s.y + r.y + bs.y;
    o.z = s.z + r.z + bs.z;
    o.w = s.w + r.w + bs.w;
    ((float4*)xout)[i] = o;
    float sum  = o.x + o.y + o.z + o.w;
    float ssum = o.x * o.x + o.y * o.y + o.z * o.z + o.w * o.w;
#pragma unroll
    for (int off = 32; off > 0; off >>= 1) {
        sum  += __shfl_down(sum, off);
        ssum += __shfl_down(ssum, off);
    }
    __shared__ float red[8];
    const int wv = t >> 6;
    if ((t & 63) == 0) { red[wv] = sum; red[4 + wv] = ssum; }
    __syncthreads();
    if (t == 0) {
        red[0] = red[0] + red[1] + red[2] + red[3];
        red[4] = red[4] + red[5] + red[6] + red[7];
    }
    __syncthreads();
    const float mean = red[0] * (1.0f / 1024.0f);
    const float var  = red[4] * (1.0f / 1024.0f) - mean * mean;
    const float rstd = rsqrtf(var + 1e-5f);
    const float4 gv = ((const float4*)gw)[t];
    const float4 bv = ((const float4*)bw)[t];
    u16x4 ov;
    ov[0] = f2bf((o.x - mean) * rstd * gv.x + bv.x);
    ov[1] = f2bf((o.y - mean) * rstd * gv.y + bv.y);
    ov[2] = f2bf((o.z - mean) * rstd * gv.z + bv.z);
    ov[3] = f2bf((o.w - mean) * rstd * gv.w + bv.w);
    ((u16x4*)lnout)[(size_t)row * 256 + t] = ov;
}

// ---------------- causal flash attention (unpaired, XCD-grouped, 2 blocks/CU) ----------
DEVI void stage_kv2(const char* kbase, const char* vbase, int key0,
                    u16* ksm, u16* vsm, int wv, int lane) {
#pragma unroll
    for (int i = 0; i < 2; ++i) {
        const int c = wv + i * 4;
        const int off = c * 1024 + lane * 16;
        const int row = off >> 7;
        const int scol = (off & 127) ^ ((row & 7) << 4);
        async_copy16(kbase + (size_t)key0 * 128 + (size_t)row * 128 + scol,
                     (char*)ksm + c * 1024);
    }
#pragma unroll
    for (int i = 0; i < 2; ++i) {
        const int c = wv + i * 4;
        const int row = c * 8 + (lane >> 3);
        const int scol = ((lane & 7) * 16) ^ ((row & 7) << 4);
        async_copy16(vbase + (size_t)row * 4096 + (size_t)key0 * 2 + scol,
                     (char*)vsm + c * 1024);
    }
}

__global__ __launch_bounds__(256, 3) void attn32_kernel(const u16* __restrict__ Q,
                                                        const u16* __restrict__ Kk,
                                                        const u16* __restrict__ Vt,
                                                        u16* __restrict__ Y) {
    const int id = blockIdx.x;
    const int bh = id & 31;                    // XCD = id % 8 = bh % 8 -> K/V L2-resident
    const int qb = 15 - (id >> 5);             // longest chains dispatch first
    const int b_ = bh >> 4, hh = bh & 15;
    const int tid = threadIdx.x;
    const int wv = tid >> 6, lane = tid & 63;
    const int hi = lane >> 5, qc = lane & 31;

    __shared__ __align__(16) u16 Ksm[2][4096];
    __shared__ __align__(16) u16 Vsm[2][4096];
    __shared__ __align__(16) u16 Pl[4][32 * 68];   // per-wave P[q][key], stride 68 u16

    const char* Kb = (const char*)(Kk + (size_t)bh * 2048 * 64);
    const char* Vb = (const char*)(Vt + (size_t)bh * 64 * 2048);
    u16* Pw = &Pl[wv][0];

    const int q0w = qb * 128 + wv * 32;
    const int qg = q0w + qc;
    const int ntile = qb * 2 + 2;
    const int ntile_w = qb * 2 + (wv >> 1) + 1;   // per-wave causal clamp

    bf16x8 qf[4];
    {
        const u16* Qp = Q + ((size_t)bh * 2048 + qg) * 64;
#pragma unroll
        for (int c = 0; c < 4; ++c)
            qf[c] = *(const bf16x8*)(Qp + c * 16 + hi * 8);
    }

    f32x16 oacc[2];
#pragma unroll
    for (int r = 0; r < 16; ++r) { oacc[0][r] = 0.0f; oacc[1][r] = 0.0f; }
    float m_run = -60000.0f, l_run = 0.0f;

    stage_kv2(Kb, Vb, 0, Ksm[0], Vsm[0], wv, lane);
    __syncthreads();
    int cur = 0;
    for (int kt = 0; kt < ntile; ++kt) {
        const int key0 = kt * 64;
        if (kt + 1 < ntile)
            stage_kv2(Kb, Vb, key0 + 64, Ksm[cur ^ 1], Vsm[cur ^ 1], wv, lane);
        if (kt < ntile_w) {
            // S^T = K * Q^T
            f32x16 sacc[2];
#pragma unroll
            for (int r = 0; r < 16; ++r) { sacc[0][r] = 0.0f; sacc[1][r] = 0.0f; }
#pragma unroll
            for (int c = 0; c < 4; ++c) {
#pragma unroll
                for (int kb = 0; kb < 2; ++kb) {
                    const int kr = kb * 32 + qc;
                    const bf16x8 ak = *(const bf16x8*)((const char*)Ksm[cur] + kr * 128 +
                                          ((c * 32 + hi * 16) ^ ((kr & 7) << 4)));
                    sacc[kb] = __builtin_amdgcn_mfma_f32_32x32x16_bf16(ak, qf[c],
                                                                       sacc[kb], 0, 0, 0);
                }
            }
            float pmax = -1e30f;
            if (key0 + 63 > q0w) {
#pragma unroll
                for (int kb = 0; kb < 2; ++kb)
#pragma unroll
                    for (int r = 0; r < 16; ++r) {
                        const int key = key0 + kb * 32 + (r & 3) + 8 * (r >> 2) + 4 * hi;
                        float s = sacc[kb][r];
                        if (key > qg) s = -1e30f;
                        sacc[kb][r] = s;
                        pmax = fmaxf(pmax, s);
                    }
            } else {
#pragma unroll
                for (int kb = 0; kb < 2; ++kb)
#pragma unroll
                    for (int r = 0; r < 16; ++r) pmax = fmaxf(pmax, sacc[kb][r]);
            }
            pmax = fmaxf(pmax, __shfl_xor(pmax, 32));
            if (pmax > m_run + 11.0f) {          // defer-max
                const float alpha = __builtin_amdgcn_exp2f(m_run - pmax);
#pragma unroll
                for (int r = 0; r < 16; ++r) { oacc[0][r] *= alpha; oacc[1][r] *= alpha; }
                l_run *= alpha;
                m_run = pmax;
            }
            float lsum = 0.0f;
#pragma unroll
            for (int kb = 0; kb < 2; ++kb)
#pragma unroll
                for (int j = 0; j < 4; ++j) {
                    u16x4 pk4;
#pragma unroll
                    for (int t = 0; t < 4; ++t) {
                        const float e = __builtin_amdgcn_exp2f(sacc[kb][j * 4 + t] - m_run);
                        lsum += e;
                        pk4[t] = f2bf(e);
                    }
                    *(u16x4*)(Pw + qc * 68 + kb * 32 + j * 8 + 4 * hi) = pk4;
                }
            lsum += __shfl_xor(lsum, 32);
            l_run += lsum;
            // O^T += V^T * P  (P read as two 8B bf16x4 loads: 2-way banks)
#pragma unroll
            for (int c = 0; c < 4; ++c) {
                const u16* pp = Pw + qc * 68 + c * 16 + hi * 8;
                union { bf16x8 v; struct { bf16x4 lo; bf16x4 hi2; } s; } u;
                u.s.lo  = *(const bf16x4*)(pp);
                u.s.hi2 = *(const bf16x4*)(pp + 4);
                const bf16x8 pf = u.v;
#pragma unroll
                for (int db = 0; db < 2; ++db) {
                    const int dr = db * 32 + qc;
                    const bf16x8 av = *(const bf16x8*)((const char*)Vsm[cur] + dr * 128 +
                                          ((c * 32 + hi * 16) ^ ((dr & 7) << 4)));
                    oacc[db] = __builtin_amdgcn_mfma_f32_32x32x16_bf16(av, pf,
                                                                       oacc[db], 0, 0, 0);
                }
            }
        }
        __syncthreads();
        cur ^= 1;
    }
    const float inv = 1.0f / l_run;
    u16* Yp = &Y[((size_t)(b_ * 2048 + qg)) * 1024 + hh * 64];
#pragma unroll
    for (int db = 0; db < 2; ++db)
#pragma unroll
        for (int j = 0; j < 4; ++j) {
            u16x4 o;
#pragma unroll
            for (int t = 0; t < 4; ++t) o[t] = f2bf(oacc[db][j * 4 + t] * inv);
            *(u16x4*)(Yp + db * 32 + j * 8 + 4 * hi) = o;
        }
}

// ---------------- host ----------------
extern "C" void kernel_launch(void* const* d_in, const int* in_sizes, int n_in,
                              void* d_out, int out_size, void* d_ws, size_t ws_size,
                              hipStream_t stream) {
    (void)in_sizes; (void)n_in; (void)out_size;
    const float* x      = (const float*)d_in[0];
    const float* w_qkv  = (const float*)d_in[2];
    const float* b_qkv  = (const float*)d_in[3];
    const float* w_proj = (const float*)d_in[4];
    const float* b_proj = (const float*)d_in[5];
    const float* w_fc1  = (const float*)d_in[6];
    const float* b_fc1  = (const float*)d_in[7];
    const float* w_fc2  = (const float*)d_in[8];
    const float* b_fc2  = (const float*)d_in[9];
    const float* g1     = (const float*)d_in[10];
    const float* be1    = (const float*)d_in[11];
    const float* g2     = (const float*)d_in[12];
    const float* be2    = (const float*)d_in[13];

    char* ws = (char*)d_ws;
    size_t off = 0;
    auto alloc = [&](size_t bytes) { size_t r = off; off += (bytes + 255) & ~(size_t)255; return r; };
    u16*   wt_qkv = (u16*)(ws + alloc((size_t)3072 * 1024 * 2));
    u16*   wt_prj = (u16*)(ws + alloc((size_t)1024 * 1024 * 2));
    u16*   wt_fc1 = (u16*)(ws + alloc((size_t)4096 * 1024 * 2));
    u16*   wt_fc2 = (u16*)(ws + alloc((size_t)1024 * 4096 * 2));
    u16*   hbuf   = (u16*)(ws + alloc((size_t)4096 * 1024 * 2));
    float* x1     = (float*)(ws + alloc((size_t)4096 * 1024 * 4));
    char*  big    = ws + alloc((size_t)33554432);
    u16* qb  = (u16*)(big);
    u16* kb  = (u16*)(big + 8388608);
    u16* vtb = (u16*)(big + 16777216);
    u16* yb  = (u16*)(big + 25165824);
    u16* act = (u16*)(big);
    if (off > ws_size) return;
    // bf16 split-K partials: FC2 sK4 = 4 x 8MB = 32MB (proj sK2 = 16MB reuses same region)
    const size_t part_need = (size_t)4 * 4096 * 1024 * 2;
    if ((ws_size - off) < part_need) return;
    u16* part = (u16*)(ws + off);

    const dim3 blk(256);
    // prep: 4x tcvt + LN1 in one launch (16384 blocks)
    prep_kernel<<<dim3(16384), blk, 0, stream>>>(w_qkv, wt_qkv, w_proj, wt_prj,
                                                 w_fc1, wt_fc1, w_fc2, wt_fc2,
                                                 x, g1, be1, hbuf);
    // QKV: grid 32*24 = 768
    gemmv6<0, 1><<<dim3(768), blk, 0, stream>>>(hbuf, wt_qkv, b_qkv,
                                                qb, kb, vtb, 4096, 3072, 1024);
    // attention: unpaired 16 chunks x 32 bh = 512 blocks (2/CU), XCD-grouped, longest first
    attn32_kernel<<<dim3(512), blk, 0, stream>>>(qb, kb, vtb, yb);
    // proj split-K=2 (bf16 partials): grid 512, then fused reduce+LN2 -> x1, hbuf
    gemmv6<5, 2><<<dim3(512), blk, 0, stream>>>(yb, wt_prj, nullptr,
                                                part, nullptr, nullptr, 4096, 1024, 1024);
    reduceLN_kernel<2><<<dim3(4096), blk, 0, stream>>>(part, b_proj, x, g2, be2,
                                                       x1, hbuf, 1048576);
    // FC1 + GELU: grid 1024
    gemmv6<2, 1><<<dim3(1024), blk, 0, stream>>>(hbuf, wt_fc1, b_fc1,
                                                 act, nullptr, nullptr, 4096, 4096, 1024);
    // FC2 split-K=4 (bf16 partials): grid 1024, then reduce(+bias+x1) -> d_out
    gemmv6<5, 4><<<dim3(1024), blk, 0, stream>>>(act, wt_fc2, nullptr,
                                                 part, nullptr, nullptr, 4096, 1024, 4096);
    reduceN_kernel<4><<<dim3(4096), blk, 0, stream>>>(part, b_fc2, x1, (float*)d_out,
                                                      1048576, 256);
}